// Round 7
// baseline (1103.338 us; speedup 1.0000x reference)
//
#include <hip/hip_runtime.h>
#include <math.h>

#define NN 50000
#define NEDGE 512000
#define DD 128

typedef short bf16x8 __attribute__((ext_vector_type(8)));
typedef float f32x4 __attribute__((ext_vector_type(4)));

__device__ __forceinline__ short f2bf(float f){
  union { float f; unsigned u; } v; v.f = f;
  unsigned u = v.u;
  return (short)((u + 0x7fffu + ((u >> 16) & 1u)) >> 16);
}
__device__ __forceinline__ float bf2f(short s){
  union { unsigned u; float f; } v; v.u = ((unsigned)(unsigned short)s) << 16; return v.f;
}

__device__ __forceinline__ bf16x8 packA(const float* __restrict__ rowp, int kbase){
  float4 x = *(const float4*)(rowp + kbase);
  float4 y = *(const float4*)(rowp + kbase + 4);
  bf16x8 r;
  r[0]=f2bf(x.x); r[1]=f2bf(x.y); r[2]=f2bf(x.z); r[3]=f2bf(x.w);
  r[4]=f2bf(y.x); r[5]=f2bf(y.y); r[6]=f2bf(y.z); r[7]=f2bf(y.w);
  return r;
}

// ------- kernel A: prep_w (blocks 0..575) + hist_dst (blocks 576..2575) -------
__global__ __launch_bounds__(256) void prep_hist(
    const float* __restrict__ Wq, const float* __restrict__ Wk,
    const float* __restrict__ Wv, const float* __restrict__ We,
    const float* __restrict__ Wo, const float* __restrict__ W1,
    const float* __restrict__ W2, short* __restrict__ wdst,
    const int* __restrict__ dst, int* __restrict__ counts){
  if (blockIdx.x >= 576){
    int id = (blockIdx.x-576)*256 + threadIdx.x;
    if (id < NEDGE) atomicAdd(&counts[dst[id]], 1);
    return;
  }
  int id = blockIdx.x*256 + threadIdx.x;
  const float* src; short* dstp; int K, NCOL, local;
  if (id < 81920){
    int m = id >> 14; local = id & 16383; K = 128; NCOL = 128;
    src = (m==0)?Wq:(m==1)?Wk:(m==2)?Wv:(m==3)?We:Wo;
    dstp = wdst + m*16384;
  } else if (id < 114688){
    local = id - 81920; K = 128; NCOL = 256; src = W1; dstp = wdst + 81920;
  } else if (id < 147456){
    local = id - 114688; K = 256; NCOL = 128; src = W2; dstp = wdst + 114688;
  } else return;
  int k = local / NCOL, n = local % NCOL;
  dstp[n*K + k] = f2bf(src[local]);
}

__global__ __launch_bounds__(256) void scan_counts(
    const int* __restrict__ counts, int* __restrict__ off){
  __shared__ int ps[256];
  int t = threadIdx.x;
  int base = t*196;
  int sum = 0;
  for (int i=0;i<196;i++){ int idx=base+i; if (idx<NN) sum += counts[idx]; }
  ps[t] = sum; __syncthreads();
  for (int o=1;o<256;o<<=1){
    int v2 = (t>=o) ? ps[t-o] : 0;
    __syncthreads();
    ps[t] += v2;
    __syncthreads();
  }
  int run = ps[t] - sum;
  for (int i=0;i<196;i++){
    int idx = base+i;
    if (idx < NN){ off[idx] = run; run += counts[idx]; }
  }
  if (t == 255) off[NN] = run;
}

// ------- kernel B: qkv_gemm (blocks 0..781) + scatter_perm (rest) -------
__global__ __launch_bounds__(256) void qkv_scatter(
    const float* __restrict__ h, const short* __restrict__ wT,
    short* __restrict__ Qb, short* __restrict__ Kb, short* __restrict__ Vb,
    const int* __restrict__ dst, const int* __restrict__ off,
    int* __restrict__ cursor, int* __restrict__ perm){
  if (blockIdx.x >= 782){
    int id = (blockIdx.x-782)*256 + threadIdx.x;
    if (id < NEDGE){
      int d = dst[id];
      int r = atomicAdd(&cursor[d], 1);
      perm[off[d] + r] = id;
    }
    return;
  }
  const short* WqT = wT;
  const short* WkT = wT + 16384;
  const short* WvT = wT + 32768;
  int lane = threadIdx.x & 63, wave = threadIdx.x >> 6;
  int r16 = lane & 15, kg = lane >> 4;
  int rowbase = blockIdx.x*64 + wave*16;
  int arow = rowbase + r16; if (arow > NN-1) arow = NN-1;
  const float* Arow = h + (size_t)arow*DD;
  f32x4 acc[3][8];
  #pragma unroll
  for (int m=0;m<3;m++)
    #pragma unroll
    for (int j=0;j<8;j++) acc[m][j] = (f32x4){0.f,0.f,0.f,0.f};
  #pragma unroll
  for (int kc=0;kc<4;kc++){
    int kb = kc*32 + kg*8;
    bf16x8 a = packA(Arow, kb);
    #pragma unroll
    for (int j=0;j<8;j++){
      bf16x8 bq = *(const bf16x8*)(WqT + (j*16+r16)*DD + kb);
      acc[0][j] = __builtin_amdgcn_mfma_f32_16x16x32_bf16(a, bq, acc[0][j], 0,0,0);
      bf16x8 bk = *(const bf16x8*)(WkT + (j*16+r16)*DD + kb);
      acc[1][j] = __builtin_amdgcn_mfma_f32_16x16x32_bf16(a, bk, acc[1][j], 0,0,0);
      bf16x8 bv = *(const bf16x8*)(WvT + (j*16+r16)*DD + kb);
      acc[2][j] = __builtin_amdgcn_mfma_f32_16x16x32_bf16(a, bv, acc[2][j], 0,0,0);
    }
  }
  int orow0 = rowbase + kg*4;
  #pragma unroll
  for (int j=0;j<8;j++){
    #pragma unroll
    for (int r=0;r<4;r++){
      int row = orow0 + r;
      if (row < NN){
        size_t idx = (size_t)row*DD + j*16 + r16;
        Qb[idx] = f2bf(acc[0][j][r]);
        Kb[idx] = f2bf(acc[1][j][r]);
        Vb[idx] = f2bf(acc[2][j][r]);
      }
    }
  }
}

// -------- edge pass: 1024 threads, 256 edges/block, single barrier.
//   stage e->LDS(bf16,swz), Eh=e@We (MFMA), in-register scores -> sArrB,
//   eL overwritten with e+Eh, coalesced copy-out, per-wave BN partials
//   written directly to global as bf16 (no LDS stats, no 2nd barrier). --------
__global__ __launch_bounds__(1024, 8) void edge_fused(
    const float* __restrict__ e, const short* __restrict__ WeT,
    const short* __restrict__ Qb, const short* __restrict__ Kb,
    const int* __restrict__ src, const int* __restrict__ dst,
    short* __restrict__ e2p, short* __restrict__ sArrB,
    short* __restrict__ partB){
  __shared__ short eL[256*128];   // 64KB; rows [w*16,w*16+16) private to wave w
  int tid = threadIdx.x;
  int rowbase = blockIdx.x*256;
  // ---- stage: coalesced fp32 read of e -> bf16 LDS (swizzled granules) ----
  {
    int row = tid >> 2;
    int c0  = (tid & 3) * 32;
    const float* rp = e + (size_t)(rowbase+row)*DD + c0;
    #pragma unroll
    for (int g=0; g<4; ++g){
      float4 x = *(const float4*)(rp + g*8);
      float4 y = *(const float4*)(rp + g*8 + 4);
      bf16x8 v;
      v[0]=f2bf(x.x); v[1]=f2bf(x.y); v[2]=f2bf(x.z); v[3]=f2bf(x.w);
      v[4]=f2bf(y.x); v[5]=f2bf(y.y); v[6]=f2bf(y.z); v[7]=f2bf(y.w);
      int col8 = (c0 >> 3) + g;
      *(bf16x8*)&eL[row*DD + ((col8 ^ (row&7))<<3)] = v;
    }
  }
  __syncthreads();
  int lane = tid & 63, wave = tid >> 6;
  int c = lane & 15, kg = lane >> 4;
  // ---- MFMA: A from LDS (own wave's 16 rows), B = WeT (L2-resident) ----
  f32x4 acc[8];
  #pragma unroll
  for (int j=0;j<8;j++) acc[j] = (f32x4){0.f,0.f,0.f,0.f};
  int arow = wave*16 + c;
  #pragma unroll
  for (int kc=0;kc<4;kc++){
    int col8 = kc*4 + kg;
    bf16x8 a = *(const bf16x8*)&eL[arow*DD + ((col8 ^ (arow&7))<<3)];
    int kb = kc*32 + kg*8;
    #pragma unroll
    for (int j=0;j<8;j++){
      bf16x8 b = *(const bf16x8*)(WeT + (j*16+c)*DD + kb);
      acc[j] = __builtin_amdgcn_mfma_f32_16x16x32_bf16(a, b, acc[j], 0,0,0);
    }
  }
  // ---- stats + in-place v = e + Eh (wave-private rows) ----
  float ssum[8], ssq[8];
  #pragma unroll
  for (int j=0;j<8;j++){ ssum[j]=0.f; ssq[j]=0.f; }
  #pragma unroll
  for (int r=0;r<4;r++){
    int le = wave*16 + kg*4 + r;
    int sw = le & 7;
    int rowoff = le*DD;
    #pragma unroll
    for (int j=0;j<8;j++){
      int col = j*16 + c;
      int sidx = rowoff + (((col>>3) ^ sw)<<3) + (col & 7);
      float v = bf2f(eL[sidx]) + acc[j][r];
      eL[sidx] = f2bf(v);
      ssum[j] += v; ssq[j] += v*v;
    }
  }
  #pragma unroll
  for (int j=0;j<8;j++){
    ssum[j] += __shfl_xor(ssum[j],16); ssum[j] += __shfl_xor(ssum[j],32);
    ssq[j]  += __shfl_xor(ssq[j],16);  ssq[j]  += __shfl_xor(ssq[j],32);
  }
  if (kg == 0){
    size_t pb = ((size_t)blockIdx.x*16 + wave)*256;
    #pragma unroll
    for (int j=0;j<8;j++){
      partB[pb + j*16 + c]       = f2bf(ssum[j]);
      partB[pb + 128 + j*16 + c] = f2bf(ssq[j]);
    }
  }
  // ---- scores fully in-register: lanes c=0..15 of group kg hold the 16
  //      columns of head j for edge le; 4-step shfl_xor reduces the dot. ----
  #pragma unroll
  for (int r=0;r<4;r++){
    int le = wave*16 + kg*4 + r;
    int ed = rowbase + le;
    int sj = src[ed], dj = dst[ed];   // uniform within 16-lane group
    const short* kp = Kb + (size_t)sj*DD + c;
    const short* qp = Qb + (size_t)dj*DD + c;
    float sreg = 0.f;
    #pragma unroll
    for (int j=0;j<8;j++){
      float p = bf2f(kp[j*16]) * bf2f(qp[j*16]) * acc[j][r];
      p += __shfl_xor(p,1); p += __shfl_xor(p,2);
      p += __shfl_xor(p,4); p += __shfl_xor(p,8);
      if (c == j) sreg = p;
    }
    if (c < 8){
      float s = __expf(fminf(fmaxf(sreg*0.25f,-5.f),5.f));
      sArrB[(size_t)ed*8 + c] = f2bf(s);
    }
  }
  // ---- copy-out e2pre bf16 (wave-local rows, 16B/lane coalesced) ----
  #pragma unroll
  for (int it=0; it<4; ++it){
    int row = wave*16 + it*4 + (lane>>4);
    int col8 = lane & 15;
    bf16x8 v = *(const bf16x8*)&eL[row*DD + ((col8 ^ (row&7))<<3)];
    *(bf16x8*)(e2p + (size_t)(rowbase+row)*DD + col8*8) = v;
  }
}

// ------- merged: node aggregation + e2 BN stream, interleaved by blockIdx&3 -------
#define NSTREAM 4167
__global__ __launch_bounds__(256) void agg_bn(
    const int* __restrict__ off, const int* __restrict__ perm,
    const int* __restrict__ src, const short* __restrict__ sArrB,
    const short* __restrict__ Vb, short* __restrict__ hA,
    const short* __restrict__ e2p, const float* __restrict__ ssE,
    float* __restrict__ e2){
  int grp = blockIdx.x >> 2, slot = blockIdx.x & 3;
  if (slot == 3){
    // ---- pure stream: e2 = e2pre(bf16)*scale + shift -> fp32 d_out ----
    size_t gi0 = (size_t)grp*256 + threadIdx.x;
    int col0 = (int)(gi0 & 15) * 8;
    float scr[8], shr[8];
    #pragma unroll
    for (int i=0;i<8;i++){ scr[i]=ssE[col0+i]; shr[i]=ssE[DD+col0+i]; }
    size_t stride = (size_t)NSTREAM*256;
    size_t total = (size_t)NEDGE*16;
    for (size_t gi = gi0; gi < total; gi += stride){
      bf16x8 v = *(const bf16x8*)(e2p + gi*8);
      float4 o0, o1;
      o0.x = bf2f(v[0])*scr[0]+shr[0];
      o0.y = bf2f(v[1])*scr[1]+shr[1];
      o0.z = bf2f(v[2])*scr[2]+shr[2];
      o0.w = bf2f(v[3])*scr[3]+shr[3];
      o1.x = bf2f(v[4])*scr[4]+shr[4];
      o1.y = bf2f(v[5])*scr[5]+shr[5];
      o1.z = bf2f(v[6])*scr[6]+shr[6];
      o1.w = bf2f(v[7])*scr[7]+shr[7];
      *(float4*)(e2 + gi*8)     = o0;
      *(float4*)(e2 + gi*8 + 4) = o1;
    }
    return;
  }
  int nblk = grp*3 + slot;
  if (nblk >= 12500) return;
  int wave = threadIdx.x >> 6, lane = threadIdx.x & 63;
  int node = nblk*4 + wave;
  if (node >= NN) return;
  int beg = off[node], end = off[node+1];
  int col2 = lane*2;
  int hd = lane >> 3;
  float w0 = 0.f, w1 = 0.f, zh = 0.f;
  int ed = beg;
  for (; ed+3 < end; ed += 4){
    int pe0 = perm[ed],   pe1 = perm[ed+1];
    int pe2 = perm[ed+2], pe3 = perm[ed+3];
    int sj0 = src[pe0], sj1 = src[pe1], sj2 = src[pe2], sj3 = src[pe3];
    float s0 = bf2f(sArrB[(size_t)pe0*8 + hd]);
    float s1 = bf2f(sArrB[(size_t)pe1*8 + hd]);
    float s2 = bf2f(sArrB[(size_t)pe2*8 + hd]);
    float s3 = bf2f(sArrB[(size_t)pe3*8 + hd]);
    unsigned v0 = *(const unsigned*)(Vb + (size_t)sj0*DD + col2);
    unsigned v1 = *(const unsigned*)(Vb + (size_t)sj1*DD + col2);
    unsigned v2 = *(const unsigned*)(Vb + (size_t)sj2*DD + col2);
    unsigned v3 = *(const unsigned*)(Vb + (size_t)sj3*DD + col2);
    w0 += bf2f((short)(v0 & 0xffff))*s0 + bf2f((short)(v1 & 0xffff))*s1
        + bf2f((short)(v2 & 0xffff))*s2 + bf2f((short)(v3 & 0xffff))*s3;
    w1 += bf2f((short)(v0 >> 16))*s0 + bf2f((short)(v1 >> 16))*s1
        + bf2f((short)(v2 >> 16))*s2 + bf2f((short)(v3 >> 16))*s3;
    zh += s0 + s1 + s2 + s3;
  }
  for (; ed < end; ++ed){
    int pe = perm[ed];
    int sj = src[pe];
    float s = bf2f(sArrB[(size_t)pe*8 + hd]);
    unsigned vv = *(const unsigned*)(Vb + (size_t)sj*DD + col2);
    w0 += bf2f((short)(vv & 0xffff)) * s;
    w1 += bf2f((short)(vv >> 16)) * s;
    zh += s;
  }
  float inv = 1.f/(zh + 1e-6f);
  unsigned outv = (((unsigned)(unsigned short)f2bf(w1*inv)) << 16)
                |  ((unsigned)(unsigned short)f2bf(w0*inv));
  *(unsigned*)(hA + (size_t)node*DD + col2) = outv;
}

// ---------------- h2pre(bf16) = hA @ Wo + bo + h, BN partials ----------------
__global__ __launch_bounds__(256) void attn_out(
    const short* __restrict__ hA,
    const short* __restrict__ WoT, const float* __restrict__ bo,
    const float* __restrict__ h, short* __restrict__ h2pre,
    float* __restrict__ part){
  __shared__ float csum[DD], csq[DD];
  if (threadIdx.x < DD){ csum[threadIdx.x] = 0.f; csq[threadIdx.x] = 0.f; }
  __syncthreads();
  int lane = threadIdx.x & 63, wave = threadIdx.x >> 6;
  int r16 = lane & 15, kg = lane >> 4;
  int rowbase = blockIdx.x*64 + wave*16;
  int arow = rowbase + r16; if (arow > NN-1) arow = NN-1;
  const short* Arow = hA + (size_t)arow*DD;
  f32x4 acc[8];
  #pragma unroll
  for (int j=0;j<8;j++) acc[j] = (f32x4){0.f,0.f,0.f,0.f};
  #pragma unroll
  for (int kc=0;kc<4;kc++){
    int kb = kc*32 + kg*8;
    bf16x8 a = *(const bf16x8*)(Arow + kb);
    #pragma unroll
    for (int j=0;j<8;j++){
      bf16x8 b = *(const bf16x8*)(WoT + (j*16+r16)*DD + kb);
      acc[j] = __builtin_amdgcn_mfma_f32_16x16x32_bf16(a, b, acc[j], 0,0,0);
    }
  }
  int orow0 = rowbase + kg*4;
  #pragma unroll
  for (int j=0;j<8;j++){
    #pragma unroll
    for (int r=0;r<4;r++){
      int row = orow0 + r;
      if (row < NN){
        int col = j*16 + r16;
        float v = acc[j][r] + bo[col] + h[(size_t)row*DD + col];
        h2pre[(size_t)row*DD + col] = f2bf(v);
        atomicAdd(&csum[col], v);
        atomicAdd(&csq[col], v*v);
      }
    }
  }
  __syncthreads();
  if (threadIdx.x < DD){
    part[(size_t)blockIdx.x*256 + threadIdx.x]      = csum[threadIdx.x];
    part[(size_t)blockIdx.x*256 + DD + threadIdx.x] = csq[threadIdx.x];
  }
}

// ---------------- FFN1: relu(BN1(h2pre) @ W1 + b1) -> bf16 ----------------
__global__ __launch_bounds__(256) void ffn1_gemm(
    const short* __restrict__ h2pre, const float* __restrict__ ss1,
    const short* __restrict__ W1T, const float* __restrict__ b1,
    short* __restrict__ ffn1){
  int lane = threadIdx.x & 63, wave = threadIdx.x >> 6;
  int r16 = lane & 15, kg = lane >> 4;
  int rowbase = blockIdx.x*64 + wave*16;
  int arow = rowbase + r16; if (arow > NN-1) arow = NN-1;
  const short* Arow = h2pre + (size_t)arow*DD;
  f32x4 acc[16];
  #pragma unroll
  for (int j=0;j<16;j++) acc[j] = (f32x4){0.f,0.f,0.f,0.f};
  #pragma unroll
  for (int kc=0;kc<4;kc++){
    int kb = kc*32 + kg*8;
    bf16x8 raw = *(const bf16x8*)(Arow + kb);
    float4 s0 = *(const float4*)(ss1 + kb);
    float4 s1 = *(const float4*)(ss1 + kb + 4);
    float4 t0 = *(const float4*)(ss1 + DD + kb);
    float4 t1 = *(const float4*)(ss1 + DD + kb + 4);
    bf16x8 a;
    a[0]=f2bf(bf2f(raw[0])*s0.x+t0.x); a[1]=f2bf(bf2f(raw[1])*s0.y+t0.y);
    a[2]=f2bf(bf2f(raw[2])*s0.z+t0.z); a[3]=f2bf(bf2f(raw[3])*s0.w+t0.w);
    a[4]=f2bf(bf2f(raw[4])*s1.x+t1.x); a[5]=f2bf(bf2f(raw[5])*s1.y+t1.y);
    a[6]=f2bf(bf2f(raw[6])*s1.z+t1.z); a[7]=f2bf(bf2f(raw[7])*s1.w+t1.w);
    #pragma unroll
    for (int j=0;j<16;j++){
      bf16x8 b = *(const bf16x8*)(W1T + (j*16+r16)*DD + kb);
      acc[j] = __builtin_amdgcn_mfma_f32_16x16x32_bf16(a, b, acc[j], 0,0,0);
    }
  }
  int orow0 = rowbase + kg*4;
  #pragma unroll
  for (int j=0;j<16;j++){
    #pragma unroll
    for (int r=0;r<4;r++){
      int row = orow0 + r;
      if (row < NN){
        int col = j*16 + r16;
        float v = fmaxf(acc[j][r] + b1[col], 0.f);
        ffn1[(size_t)row*256 + col] = f2bf(v);
      }
    }
  }
}

// ---------------- FFN2: h3pre = BN1(h2pre) + ffn1 @ W2 + b2, BN partials ----------------
__global__ __launch_bounds__(256) void ffn2_gemm(
    const short* __restrict__ ffn1, const short* __restrict__ W2T,
    const float* __restrict__ b2, const short* __restrict__ h2pre,
    const float* __restrict__ ss1, float* __restrict__ h3pre,
    float* __restrict__ part){
  __shared__ float csum[DD], csq[DD];
  if (threadIdx.x < DD){ csum[threadIdx.x] = 0.f; csq[threadIdx.x] = 0.f; }
  __syncthreads();
  int lane = threadIdx.x & 63, wave = threadIdx.x >> 6;
  int r16 = lane & 15, kg = lane >> 4;
  int rowbase = blockIdx.x*64 + wave*16;
  int arow = rowbase + r16; if (arow > NN-1) arow = NN-1;
  const short* Arow = ffn1 + (size_t)arow*256;
  f32x4 acc[8];
  #pragma unroll
  for (int j=0;j<8;j++) acc[j] = (f32x4){0.f,0.f,0.f,0.f};
  #pragma unroll
  for (int kc=0;kc<8;kc++){
    int kb = kc*32 + kg*8;
    bf16x8 a = *(const bf16x8*)(Arow + kb);
    #pragma unroll
    for (int j=0;j<8;j++){
      bf16x8 b = *(const bf16x8*)(W2T + (j*16+r16)*256 + kb);
      acc[j] = __builtin_amdgcn_mfma_f32_16x16x32_bf16(a, b, acc[j], 0,0,0);
    }
  }
  int orow0 = rowbase + kg*4;
  #pragma unroll
  for (int j=0;j<8;j++){
    #pragma unroll
    for (int r=0;r<4;r++){
      int row = orow0 + r;
      if (row < NN){
        int col = j*16 + r16;
        float x = bf2f(h2pre[(size_t)row*DD + col]);
        float h2bn = x*ss1[col] + ss1[DD+col];
        float v = h2bn + acc[j][r] + b2[col];
        h3pre[(size_t)row*DD + col] = v;
        atomicAdd(&csum[col], v);
        atomicAdd(&csq[col], v*v);
      }
    }
  }
  __syncthreads();
  if (threadIdx.x < DD){
    part[(size_t)blockIdx.x*256 + threadIdx.x]      = csum[threadIdx.x];
    part[(size_t)blockIdx.x*256 + DD + threadIdx.x] = csq[threadIdx.x];
  }
}

// ---------------- BN stats reduce (fp32 partials) ----------------
__global__ __launch_bounds__(256) void bn_reduce(
    const float* __restrict__ part, int nparts, float inv_n,
    const float* __restrict__ g, const float* __restrict__ b,
    float* __restrict__ ss){
  int col = blockIdx.x, t = threadIdx.x;
  float s = 0.f, q = 0.f;
  for (int i=t; i<nparts; i+=256){
    s += part[(size_t)i*256 + col];
    q += part[(size_t)i*256 + DD + col];
  }
  __shared__ float ls[256], lq[256];
  ls[t] = s; lq[t] = q; __syncthreads();
  for (int o2=128; o2>0; o2>>=1){
    if (t < o2){ ls[t] += ls[t+o2]; lq[t] += lq[t+o2]; }
    __syncthreads();
  }
  if (t == 0){
    float mean = ls[0]*inv_n;
    float var  = lq[0]*inv_n - mean*mean;
    float sc = g[col]*rsqrtf(var + 1e-5f);
    ss[col]      = sc;
    ss[DD + col] = b[col] - mean*sc;
  }
}

// ---------------- BN stats reduce (bf16 partials) ----------------
__global__ __launch_bounds__(256) void bn_reduce_bf16(
    const short* __restrict__ part, int nparts, float inv_n,
    const float* __restrict__ g, const float* __restrict__ b,
    float* __restrict__ ss){
  int col = blockIdx.x, t = threadIdx.x;
  float s = 0.f, q = 0.f;
  for (int i=t; i<nparts; i+=256){
    s += bf2f(part[(size_t)i*256 + col]);
    q += bf2f(part[(size_t)i*256 + DD + col]);
  }
  __shared__ float ls[256], lq[256];
  ls[t] = s; lq[t] = q; __syncthreads();
  for (int o2=128; o2>0; o2>>=1){
    if (t < o2){ ls[t] += ls[t+o2]; lq[t] += lq[t+o2]; }
    __syncthreads();
  }
  if (t == 0){
    float mean = ls[0]*inv_n;
    float var  = lq[0]*inv_n - mean*mean;
    float sc = g[col]*rsqrtf(var + 1e-5f);
    ss[col]      = sc;
    ss[DD + col] = b[col] - mean*sc;
  }
}

// ---------------- in-place BN apply (h3 only): x = x*scale + shift ----------------
__global__ __launch_bounds__(256) void bn_apply(
    float* __restrict__ x, size_t rows, const float* __restrict__ ss){
  size_t id = (size_t)blockIdx.x*256 + threadIdx.x;
  size_t total = rows*32;
  if (id >= total) return;
  float4* p = (float4*)x + id;
  int c = (int)(id & 31) * 4;
  float4 v = *p;
  v.x = v.x*ss[c]   + ss[DD+c];
  v.y = v.y*ss[c+1] + ss[DD+c+1];
  v.z = v.z*ss[c+2] + ss[DD+c+2];
  v.w = v.w*ss[c+3] + ss[DD+c+3];
  *p = v;
}

extern "C" void kernel_launch(void* const* d_in, const int* in_sizes, int n_in,
                              void* d_out, int out_size, void* d_ws, size_t ws_size,
                              hipStream_t stream){
  const float* h   = (const float*)d_in[0];
  const float* e   = (const float*)d_in[1];
  const int*   src = (const int*)d_in[2];
  const int*   dst = (const int*)d_in[3];
  const float* Wq  = (const float*)d_in[4];
  const float* Wk  = (const float*)d_in[5];
  const float* Wv  = (const float*)d_in[6];
  const float* We  = (const float*)d_in[7];
  const float* Wo  = (const float*)d_in[8];
  const float* bo  = (const float*)d_in[9];
  const float* g1h = (const float*)d_in[10];
  const float* b1h = (const float*)d_in[11];
  const float* g1e = (const float*)d_in[12];
  const float* b1e = (const float*)d_in[13];
  const float* W1  = (const float*)d_in[14];
  const float* b1  = (const float*)d_in[15];
  const float* W2  = (const float*)d_in[16];
  const float* b2  = (const float*)d_in[17];
  const float* g2h = (const float*)d_in[18];
  const float* b2h = (const float*)d_in[19];

  float* out = (float*)d_out;
  float* h3  = out;                       // [NN][128]
  float* e2  = out + (size_t)NN*DD;       // [NEDGE][128]

  char* ws = (char*)d_ws;
  size_t off_b = 0;
  auto take = [&](size_t bytes)->char*{
    char* p = ws + off_b; off_b = (off_b + bytes + 255) & ~(size_t)255; return p;
  };
  short* wT     = (short*)take((size_t)147456*2);
  float* ssE    = (float*)take(256*4);
  float* ss1    = (float*)take(256*4);
  float* ss2    = (float*)take(256*4);
  short* Qb     = (short*)take((size_t)NN*DD*2);
  short* Kb     = (short*)take((size_t)NN*DD*2);
  short* Vb     = (short*)take((size_t)NN*DD*2);
  short* hA     = (short*)take((size_t)NN*DD*2);
  short* e2p    = (short*)take((size_t)NEDGE*DD*2);
  short* sArrB  = (short*)take((size_t)NEDGE*8*2);
  int*   cnt2   = (int*)take((size_t)2*NN*4);     // counts | cursor
  int*   counts = cnt2;
  int*   cursor = cnt2 + NN;
  int*   offs   = (int*)take((size_t)(NN+1)*4);
  int*   perm   = (int*)take((size_t)NEDGE*4);
  short* h2pre  = (short*)take((size_t)NN*DD*2);
  short* ffn1   = (short*)take((size_t)NN*256*2);
  short* partEB = (short*)take((size_t)32000*256*2);
  float* partH2 = (float*)take((size_t)782*256*4);
  float* partH3 = (float*)take((size_t)782*256*4);

  hipMemsetAsync(cnt2, 0, (size_t)2*NN*4, stream);

  prep_hist<<<2576,256,0,stream>>>(Wq,Wk,Wv,We,Wo,W1,W2,wT, dst, counts);
  scan_counts<<<1,256,0,stream>>>(counts, offs);
  qkv_scatter<<<2782,256,0,stream>>>(h, wT, Qb, Kb, Vb, dst, offs, cursor, perm);
  edge_fused<<<2000,1024,0,stream>>>(e, wT+49152, Qb, Kb, src, dst,
                                     e2p, sArrB, partEB);
  bn_reduce_bf16<<<128,256,0,stream>>>(partEB, 32000, 1.f/(float)NEDGE, g1e, b1e, ssE);
  agg_bn<<<16668,256,0,stream>>>(offs, perm, src, sArrB, Vb, hA, e2p, ssE, e2);
  attn_out<<<782,256,0,stream>>>(hA, wT+65536, bo, h, h2pre, partH2);
  bn_reduce<<<128,256,0,stream>>>(partH2, 782, 1.f/(float)NN, g1h, b1h, ss1);
  ffn1_gemm<<<782,256,0,stream>>>(h2pre, ss1, wT+81920, b1, ffn1);
  ffn2_gemm<<<782,256,0,stream>>>(ffn1, wT+114688, b2, h2pre, ss1, h3, partH3);
  bn_reduce<<<128,256,0,stream>>>(partH3, 782, 1.f/(float)NN, g2h, b2h, ss2);
  bn_apply<<<6250,256,0,stream>>>(h3, (size_t)NN, ss2);
}

// Round 8
// 885.900 us; speedup vs baseline: 1.2454x; 1.2454x over previous
//
#include <hip/hip_runtime.h>
#include <math.h>

#define NN 50000
#define NEDGE 512000
#define DD 128

typedef short bf16x8 __attribute__((ext_vector_type(8)));
typedef float f32x4 __attribute__((ext_vector_type(4)));

__device__ __forceinline__ short f2bf(float f){
  union { float f; unsigned u; } v; v.f = f;
  unsigned u = v.u;
  return (short)((u + 0x7fffu + ((u >> 16) & 1u)) >> 16);
}
__device__ __forceinline__ float bf2f(short s){
  union { unsigned u; float f; } v; v.u = ((unsigned)(unsigned short)s) << 16; return v.f;
}

__device__ __forceinline__ bf16x8 packA(const float* __restrict__ rowp, int kbase){
  float4 x = *(const float4*)(rowp + kbase);
  float4 y = *(const float4*)(rowp + kbase + 4);
  bf16x8 r;
  r[0]=f2bf(x.x); r[1]=f2bf(x.y); r[2]=f2bf(x.z); r[3]=f2bf(x.w);
  r[4]=f2bf(y.x); r[5]=f2bf(y.y); r[6]=f2bf(y.z); r[7]=f2bf(y.w);
  return r;
}

// ------- kernel A: prep_w (blocks 0..575) + hist_dst (blocks 576..2575) -------
__global__ __launch_bounds__(256) void prep_hist(
    const float* __restrict__ Wq, const float* __restrict__ Wk,
    const float* __restrict__ Wv, const float* __restrict__ We,
    const float* __restrict__ Wo, const float* __restrict__ W1,
    const float* __restrict__ W2, short* __restrict__ wdst,
    const int* __restrict__ dst, int* __restrict__ counts){
  if (blockIdx.x >= 576){
    int id = (blockIdx.x-576)*256 + threadIdx.x;
    if (id < NEDGE) atomicAdd(&counts[dst[id]], 1);
    return;
  }
  int id = blockIdx.x*256 + threadIdx.x;
  const float* src; short* dstp; int K, NCOL, local;
  if (id < 81920){
    int m = id >> 14; local = id & 16383; K = 128; NCOL = 128;
    src = (m==0)?Wq:(m==1)?Wk:(m==2)?Wv:(m==3)?We:Wo;
    dstp = wdst + m*16384;
  } else if (id < 114688){
    local = id - 81920; K = 128; NCOL = 256; src = W1; dstp = wdst + 81920;
  } else if (id < 147456){
    local = id - 114688; K = 256; NCOL = 128; src = W2; dstp = wdst + 114688;
  } else return;
  int k = local / NCOL, n = local % NCOL;
  dstp[n*K + k] = f2bf(src[local]);
}

__global__ __launch_bounds__(256) void scan_counts(
    const int* __restrict__ counts, int* __restrict__ off){
  __shared__ int ps[256];
  int t = threadIdx.x;
  int base = t*196;
  int sum = 0;
  for (int i=0;i<196;i++){ int idx=base+i; if (idx<NN) sum += counts[idx]; }
  ps[t] = sum; __syncthreads();
  for (int o=1;o<256;o<<=1){
    int v2 = (t>=o) ? ps[t-o] : 0;
    __syncthreads();
    ps[t] += v2;
    __syncthreads();
  }
  int run = ps[t] - sum;
  for (int i=0;i<196;i++){
    int idx = base+i;
    if (idx < NN){ off[idx] = run; run += counts[idx]; }
  }
  if (t == 255) off[NN] = run;
}

// ------- kernel B: qkv_gemm (blocks 0..781) + scatter_perm (rest) -------
// K and Q are stored PERMUTED: XbP[node*128 + c*8 + j] = X[node][j*16+c]
// (c = within-head col 0..15, j = head 0..7)  -> edge score phase reads
// a lane's whole slice as ONE 16B load. V stays in natural layout.
__global__ __launch_bounds__(256) void qkv_scatter(
    const float* __restrict__ h, const short* __restrict__ wT,
    short* __restrict__ QbP, short* __restrict__ KbP, short* __restrict__ Vb,
    const int* __restrict__ dst, const int* __restrict__ off,
    int* __restrict__ cursor, int* __restrict__ perm){
  if (blockIdx.x >= 782){
    int id = (blockIdx.x-782)*256 + threadIdx.x;
    if (id < NEDGE){
      int d = dst[id];
      int r = atomicAdd(&cursor[d], 1);
      perm[off[d] + r] = id;
    }
    return;
  }
  const short* WqT = wT;
  const short* WkT = wT + 16384;
  const short* WvT = wT + 32768;
  int lane = threadIdx.x & 63, wave = threadIdx.x >> 6;
  int r16 = lane & 15, kg = lane >> 4;
  int rowbase = blockIdx.x*64 + wave*16;
  int arow = rowbase + r16; if (arow > NN-1) arow = NN-1;
  const float* Arow = h + (size_t)arow*DD;
  f32x4 acc[3][8];
  #pragma unroll
  for (int m=0;m<3;m++)
    #pragma unroll
    for (int j=0;j<8;j++) acc[m][j] = (f32x4){0.f,0.f,0.f,0.f};
  #pragma unroll
  for (int kc=0;kc<4;kc++){
    int kb = kc*32 + kg*8;
    bf16x8 a = packA(Arow, kb);
    #pragma unroll
    for (int j=0;j<8;j++){
      bf16x8 bq = *(const bf16x8*)(WqT + (j*16+r16)*DD + kb);
      acc[0][j] = __builtin_amdgcn_mfma_f32_16x16x32_bf16(a, bq, acc[0][j], 0,0,0);
      bf16x8 bk = *(const bf16x8*)(WkT + (j*16+r16)*DD + kb);
      acc[1][j] = __builtin_amdgcn_mfma_f32_16x16x32_bf16(a, bk, acc[1][j], 0,0,0);
      bf16x8 bv = *(const bf16x8*)(WvT + (j*16+r16)*DD + kb);
      acc[2][j] = __builtin_amdgcn_mfma_f32_16x16x32_bf16(a, bv, acc[2][j], 0,0,0);
    }
  }
  int orow0 = rowbase + kg*4;
  #pragma unroll
  for (int j=0;j<8;j++){
    #pragma unroll
    for (int r=0;r<4;r++){
      int row = orow0 + r;
      if (row < NN){
        QbP[(size_t)row*DD + r16*8 + j] = f2bf(acc[0][j][r]);   // permuted
        KbP[(size_t)row*DD + r16*8 + j] = f2bf(acc[1][j][r]);   // permuted
        Vb [(size_t)row*DD + j*16 + r16] = f2bf(acc[2][j][r]);  // natural
      }
    }
  }
}

// -------- edge pass (R6 structure, 256 thr, + vectorized score gathers,
//   + per-wave BN partials straight to global bf16; single barrier). --------
__global__ __launch_bounds__(256) void edge_fused(
    const float* __restrict__ e, const short* __restrict__ WeT,
    const short* __restrict__ QbP, const short* __restrict__ KbP,
    const int* __restrict__ src, const int* __restrict__ dst,
    short* __restrict__ e2p, short* __restrict__ sArrB,
    short* __restrict__ partB){
  __shared__ short eL[64*128];    // 16KB; rows [w*16,w*16+16) private to wave w
  int tid = threadIdx.x;
  int rowbase = blockIdx.x*64;
  // ---- stage: coalesced fp32 read of e -> bf16 LDS (swizzled granules) ----
  {
    int row = tid >> 2;
    int c0  = (tid & 3) * 32;
    const float* rp = e + (size_t)(rowbase+row)*DD + c0;
    #pragma unroll
    for (int g=0; g<4; ++g){
      float4 x = *(const float4*)(rp + g*8);
      float4 y = *(const float4*)(rp + g*8 + 4);
      bf16x8 v;
      v[0]=f2bf(x.x); v[1]=f2bf(x.y); v[2]=f2bf(x.z); v[3]=f2bf(x.w);
      v[4]=f2bf(y.x); v[5]=f2bf(y.y); v[6]=f2bf(y.z); v[7]=f2bf(y.w);
      int col8 = (c0 >> 3) + g;
      *(bf16x8*)&eL[row*DD + ((col8 ^ (row&7))<<3)] = v;
    }
  }
  __syncthreads();
  int lane = tid & 63, wave = tid >> 6;
  int c = lane & 15, kg = lane >> 4;
  // ---- MFMA: A from LDS (own wave's 16 rows), B = WeT (L2-resident) ----
  f32x4 acc[8];
  #pragma unroll
  for (int j=0;j<8;j++) acc[j] = (f32x4){0.f,0.f,0.f,0.f};
  int arow = wave*16 + c;
  #pragma unroll
  for (int kc=0;kc<4;kc++){
    int col8 = kc*4 + kg;
    bf16x8 a = *(const bf16x8*)&eL[arow*DD + ((col8 ^ (arow&7))<<3)];
    int kb = kc*32 + kg*8;
    #pragma unroll
    for (int j=0;j<8;j++){
      bf16x8 b = *(const bf16x8*)(WeT + (j*16+c)*DD + kb);
      acc[j] = __builtin_amdgcn_mfma_f32_16x16x32_bf16(a, b, acc[j], 0,0,0);
    }
  }
  // ---- issue score-phase K/Q loads EARLY (independent 16B vectors) ----
  bf16x8 kv[4], qv[4];
  #pragma unroll
  for (int r=0;r<4;r++){
    int ed = rowbase + wave*16 + kg*4 + r;
    int sj = src[ed], dj = dst[ed];
    kv[r] = *(const bf16x8*)(KbP + (size_t)sj*DD + c*8);
    qv[r] = *(const bf16x8*)(QbP + (size_t)dj*DD + c*8);
  }
  // ---- stats + in-place v = e + Eh (wave-private rows) ----
  float ssum[8], ssq[8];
  #pragma unroll
  for (int j=0;j<8;j++){ ssum[j]=0.f; ssq[j]=0.f; }
  #pragma unroll
  for (int r=0;r<4;r++){
    int le = wave*16 + kg*4 + r;
    int sw = le & 7;
    int rowoff = le*DD;
    #pragma unroll
    for (int j=0;j<8;j++){
      int col = j*16 + c;
      int sidx = rowoff + (((col>>3) ^ sw)<<3) + (col & 7);
      float v = bf2f(eL[sidx]) + acc[j][r];
      eL[sidx] = f2bf(v);
      ssum[j] += v; ssq[j] += v*v;
    }
  }
  #pragma unroll
  for (int j=0;j<8;j++){
    ssum[j] += __shfl_xor(ssum[j],16); ssum[j] += __shfl_xor(ssum[j],32);
    ssq[j]  += __shfl_xor(ssq[j],16);  ssq[j]  += __shfl_xor(ssq[j],32);
  }
  if (kg == 0){
    size_t pb = ((size_t)blockIdx.x*4 + wave)*256;
    #pragma unroll
    for (int j=0;j<8;j++){
      partB[pb + j*16 + c]       = f2bf(ssum[j]);
      partB[pb + 128 + j*16 + c] = f2bf(ssq[j]);
    }
  }
  // ---- scores: lane c holds K/Q slice (8 heads) as vectors; per head j,
  //      reduce k*q*Eh over 16 lanes. Eh lives in acc[j][r]. ----
  #pragma unroll
  for (int r=0;r<4;r++){
    int ed = rowbase + wave*16 + kg*4 + r;
    float sreg = 0.f;
    #pragma unroll
    for (int j=0;j<8;j++){
      float p = bf2f(kv[r][j]) * bf2f(qv[r][j]) * acc[j][r];
      p += __shfl_xor(p,1); p += __shfl_xor(p,2);
      p += __shfl_xor(p,4); p += __shfl_xor(p,8);
      if (c == j) sreg = p;
    }
    if (c < 8){
      float s = __expf(fminf(fmaxf(sreg*0.25f,-5.f),5.f));
      sArrB[(size_t)ed*8 + c] = f2bf(s);
    }
  }
  // ---- copy-out e2pre bf16 (wave-local rows, 16B/lane coalesced) ----
  #pragma unroll
  for (int it=0; it<4; ++it){
    int row = wave*16 + it*4 + (lane>>4);
    int col8 = lane & 15;
    bf16x8 v = *(const bf16x8*)&eL[row*DD + ((col8 ^ (row&7))<<3)];
    *(bf16x8*)(e2p + (size_t)(rowbase+row)*DD + col8*8) = v;
  }
}

// ------- merged: node aggregation (blocks 0..12499) + e2 BN stream (rest) -------
__global__ __launch_bounds__(256) void agg_bn(
    const int* __restrict__ off, const int* __restrict__ perm,
    const int* __restrict__ src, const short* __restrict__ sArrB,
    const short* __restrict__ Vb, short* __restrict__ hA,
    const short* __restrict__ e2p, const float* __restrict__ ssE,
    float* __restrict__ e2){
  if (blockIdx.x >= 12500){
    // ---- pure stream: e2 = e2pre(bf16)*scale + shift -> fp32 d_out ----
    size_t gi0 = (size_t)(blockIdx.x-12500)*256 + threadIdx.x;
    int col0 = (int)(gi0 & 15) * 8;
    float scr[8], shr[8];
    #pragma unroll
    for (int i=0;i<8;i++){ scr[i]=ssE[col0+i]; shr[i]=ssE[DD+col0+i]; }
    size_t stride = (size_t)2048*256;
    size_t total = (size_t)NEDGE*16;
    for (size_t gi = gi0; gi < total; gi += stride){
      bf16x8 v = *(const bf16x8*)(e2p + gi*8);
      float4 o0, o1;
      o0.x = bf2f(v[0])*scr[0]+shr[0];
      o0.y = bf2f(v[1])*scr[1]+shr[1];
      o0.z = bf2f(v[2])*scr[2]+shr[2];
      o0.w = bf2f(v[3])*scr[3]+shr[3];
      o1.x = bf2f(v[4])*scr[4]+shr[4];
      o1.y = bf2f(v[5])*scr[5]+shr[5];
      o1.z = bf2f(v[6])*scr[6]+shr[6];
      o1.w = bf2f(v[7])*scr[7]+shr[7];
      *(float4*)(e2 + gi*8)     = o0;
      *(float4*)(e2 + gi*8 + 4) = o1;
    }
    return;
  }
  int wave = threadIdx.x >> 6, lane = threadIdx.x & 63;
  int node = blockIdx.x*4 + wave;
  if (node >= NN) return;
  int beg = off[node], end = off[node+1];
  int col2 = lane*2;
  int hd = lane >> 3;
  float w0 = 0.f, w1 = 0.f, zh = 0.f;
  int ed = beg;
  for (; ed+3 < end; ed += 4){
    int pe0 = perm[ed],   pe1 = perm[ed+1];
    int pe2 = perm[ed+2], pe3 = perm[ed+3];
    int sj0 = src[pe0], sj1 = src[pe1], sj2 = src[pe2], sj3 = src[pe3];
    float s0 = bf2f(sArrB[(size_t)pe0*8 + hd]);
    float s1 = bf2f(sArrB[(size_t)pe1*8 + hd]);
    float s2 = bf2f(sArrB[(size_t)pe2*8 + hd]);
    float s3 = bf2f(sArrB[(size_t)pe3*8 + hd]);
    unsigned v0 = *(const unsigned*)(Vb + (size_t)sj0*DD + col2);
    unsigned v1 = *(const unsigned*)(Vb + (size_t)sj1*DD + col2);
    unsigned v2 = *(const unsigned*)(Vb + (size_t)sj2*DD + col2);
    unsigned v3 = *(const unsigned*)(Vb + (size_t)sj3*DD + col2);
    w0 += bf2f((short)(v0 & 0xffff))*s0 + bf2f((short)(v1 & 0xffff))*s1
        + bf2f((short)(v2 & 0xffff))*s2 + bf2f((short)(v3 & 0xffff))*s3;
    w1 += bf2f((short)(v0 >> 16))*s0 + bf2f((short)(v1 >> 16))*s1
        + bf2f((short)(v2 >> 16))*s2 + bf2f((short)(v3 >> 16))*s3;
    zh += s0 + s1 + s2 + s3;
  }
  for (; ed < end; ++ed){
    int pe = perm[ed];
    int sj = src[pe];
    float s = bf2f(sArrB[(size_t)pe*8 + hd]);
    unsigned vv = *(const unsigned*)(Vb + (size_t)sj*DD + col2);
    w0 += bf2f((short)(vv & 0xffff)) * s;
    w1 += bf2f((short)(vv >> 16)) * s;
    zh += s;
  }
  float inv = 1.f/(zh + 1e-6f);
  unsigned outv = (((unsigned)(unsigned short)f2bf(w1*inv)) << 16)
                |  ((unsigned)(unsigned short)f2bf(w0*inv));
  *(unsigned*)(hA + (size_t)node*DD + col2) = outv;
}

// ---------------- h2pre(bf16) = hA @ Wo + bo + h, BN partials ----------------
__global__ __launch_bounds__(256) void attn_out(
    const short* __restrict__ hA,
    const short* __restrict__ WoT, const float* __restrict__ bo,
    const float* __restrict__ h, short* __restrict__ h2pre,
    float* __restrict__ part){
  __shared__ float csum[DD], csq[DD];
  if (threadIdx.x < DD){ csum[threadIdx.x] = 0.f; csq[threadIdx.x] = 0.f; }
  __syncthreads();
  int lane = threadIdx.x & 63, wave = threadIdx.x >> 6;
  int r16 = lane & 15, kg = lane >> 4;
  int rowbase = blockIdx.x*64 + wave*16;
  int arow = rowbase + r16; if (arow > NN-1) arow = NN-1;
  const short* Arow = hA + (size_t)arow*DD;
  f32x4 acc[8];
  #pragma unroll
  for (int j=0;j<8;j++) acc[j] = (f32x4){0.f,0.f,0.f,0.f};
  #pragma unroll
  for (int kc=0;kc<4;kc++){
    int kb = kc*32 + kg*8;
    bf16x8 a = *(const bf16x8*)(Arow + kb);
    #pragma unroll
    for (int j=0;j<8;j++){
      bf16x8 b = *(const bf16x8*)(WoT + (j*16+r16)*DD + kb);
      acc[j] = __builtin_amdgcn_mfma_f32_16x16x32_bf16(a, b, acc[j], 0,0,0);
    }
  }
  int orow0 = rowbase + kg*4;
  #pragma unroll
  for (int j=0;j<8;j++){
    #pragma unroll
    for (int r=0;r<4;r++){
      int row = orow0 + r;
      if (row < NN){
        int col = j*16 + r16;
        float v = acc[j][r] + bo[col] + h[(size_t)row*DD + col];
        h2pre[(size_t)row*DD + col] = f2bf(v);
        atomicAdd(&csum[col], v);
        atomicAdd(&csq[col], v*v);
      }
    }
  }
  __syncthreads();
  if (threadIdx.x < DD){
    part[(size_t)blockIdx.x*256 + threadIdx.x]      = csum[threadIdx.x];
    part[(size_t)blockIdx.x*256 + DD + threadIdx.x] = csq[threadIdx.x];
  }
}

// ---------------- FFN1: relu(BN1(h2pre) @ W1 + b1) -> bf16 ----------------
__global__ __launch_bounds__(256) void ffn1_gemm(
    const short* __restrict__ h2pre, const float* __restrict__ ss1,
    const short* __restrict__ W1T, const float* __restrict__ b1,
    short* __restrict__ ffn1){
  int lane = threadIdx.x & 63, wave = threadIdx.x >> 6;
  int r16 = lane & 15, kg = lane >> 4;
  int rowbase = blockIdx.x*64 + wave*16;
  int arow = rowbase + r16; if (arow > NN-1) arow = NN-1;
  const short* Arow = h2pre + (size_t)arow*DD;
  f32x4 acc[16];
  #pragma unroll
  for (int j=0;j<16;j++) acc[j] = (f32x4){0.f,0.f,0.f,0.f};
  #pragma unroll
  for (int kc=0;kc<4;kc++){
    int kb = kc*32 + kg*8;
    bf16x8 raw = *(const bf16x8*)(Arow + kb);
    float4 s0 = *(const float4*)(ss1 + kb);
    float4 s1 = *(const float4*)(ss1 + kb + 4);
    float4 t0 = *(const float4*)(ss1 + DD + kb);
    float4 t1 = *(const float4*)(ss1 + DD + kb + 4);
    bf16x8 a;
    a[0]=f2bf(bf2f(raw[0])*s0.x+t0.x); a[1]=f2bf(bf2f(raw[1])*s0.y+t0.y);
    a[2]=f2bf(bf2f(raw[2])*s0.z+t0.z); a[3]=f2bf(bf2f(raw[3])*s0.w+t0.w);
    a[4]=f2bf(bf2f(raw[4])*s1.x+t1.x); a[5]=f2bf(bf2f(raw[5])*s1.y+t1.y);
    a[6]=f2bf(bf2f(raw[6])*s1.z+t1.z); a[7]=f2bf(bf2f(raw[7])*s1.w+t1.w);
    #pragma unroll
    for (int j=0;j<16;j++){
      bf16x8 b = *(const bf16x8*)(W1T + (j*16+r16)*DD + kb);
      acc[j] = __builtin_amdgcn_mfma_f32_16x16x32_bf16(a, b, acc[j], 0,0,0);
    }
  }
  int orow0 = rowbase + kg*4;
  #pragma unroll
  for (int j=0;j<16;j++){
    #pragma unroll
    for (int r=0;r<4;r++){
      int row = orow0 + r;
      if (row < NN){
        int col = j*16 + r16;
        float v = fmaxf(acc[j][r] + b1[col], 0.f);
        ffn1[(size_t)row*256 + col] = f2bf(v);
      }
    }
  }
}

// ---------------- FFN2: h3pre = BN1(h2pre) + ffn1 @ W2 + b2, BN partials ----------------
__global__ __launch_bounds__(256) void ffn2_gemm(
    const short* __restrict__ ffn1, const short* __restrict__ W2T,
    const float* __restrict__ b2, const short* __restrict__ h2pre,
    const float* __restrict__ ss1, float* __restrict__ h3pre,
    float* __restrict__ part){
  __shared__ float csum[DD], csq[DD];
  if (threadIdx.x < DD){ csum[threadIdx.x] = 0.f; csq[threadIdx.x] = 0.f; }
  __syncthreads();
  int lane = threadIdx.x & 63, wave = threadIdx.x >> 6;
  int r16 = lane & 15, kg = lane >> 4;
  int rowbase = blockIdx.x*64 + wave*16;
  int arow = rowbase + r16; if (arow > NN-1) arow = NN-1;
  const short* Arow = ffn1 + (size_t)arow*256;
  f32x4 acc[8];
  #pragma unroll
  for (int j=0;j<8;j++) acc[j] = (f32x4){0.f,0.f,0.f,0.f};
  #pragma unroll
  for (int kc=0;kc<8;kc++){
    int kb = kc*32 + kg*8;
    bf16x8 a = *(const bf16x8*)(Arow + kb);
    #pragma unroll
    for (int j=0;j<8;j++){
      bf16x8 b = *(const bf16x8*)(W2T + (j*16+r16)*256 + kb);
      acc[j] = __builtin_amdgcn_mfma_f32_16x16x32_bf16(a, b, acc[j], 0,0,0);
    }
  }
  int orow0 = rowbase + kg*4;
  #pragma unroll
  for (int j=0;j<8;j++){
    #pragma unroll
    for (int r=0;r<4;r++){
      int row = orow0 + r;
      if (row < NN){
        int col = j*16 + r16;
        float x = bf2f(h2pre[(size_t)row*DD + col]);
        float h2bn = x*ss1[col] + ss1[DD+col];
        float v = h2bn + acc[j][r] + b2[col];
        h3pre[(size_t)row*DD + col] = v;
        atomicAdd(&csum[col], v);
        atomicAdd(&csq[col], v*v);
      }
    }
  }
  __syncthreads();
  if (threadIdx.x < DD){
    part[(size_t)blockIdx.x*256 + threadIdx.x]      = csum[threadIdx.x];
    part[(size_t)blockIdx.x*256 + DD + threadIdx.x] = csq[threadIdx.x];
  }
}

// ---------------- BN stats reduce (fp32 partials) ----------------
__global__ __launch_bounds__(256) void bn_reduce(
    const float* __restrict__ part, int nparts, float inv_n,
    const float* __restrict__ g, const float* __restrict__ b,
    float* __restrict__ ss){
  int col = blockIdx.x, t = threadIdx.x;
  float s = 0.f, q = 0.f;
  for (int i=t; i<nparts; i+=256){
    s += part[(size_t)i*256 + col];
    q += part[(size_t)i*256 + DD + col];
  }
  __shared__ float ls[256], lq[256];
  ls[t] = s; lq[t] = q; __syncthreads();
  for (int o2=128; o2>0; o2>>=1){
    if (t < o2){ ls[t] += ls[t+o2]; lq[t] += lq[t+o2]; }
    __syncthreads();
  }
  if (t == 0){
    float mean = ls[0]*inv_n;
    float var  = lq[0]*inv_n - mean*mean;
    float sc = g[col]*rsqrtf(var + 1e-5f);
    ss[col]      = sc;
    ss[DD + col] = b[col] - mean*sc;
  }
}

// ---------------- BN stats reduce (bf16 partials) ----------------
__global__ __launch_bounds__(256) void bn_reduce_bf16(
    const short* __restrict__ part, int nparts, float inv_n,
    const float* __restrict__ g, const float* __restrict__ b,
    float* __restrict__ ss){
  int col = blockIdx.x, t = threadIdx.x;
  float s = 0.f, q = 0.f;
  for (int i=t; i<nparts; i+=256){
    s += bf2f(part[(size_t)i*256 + col]);
    q += bf2f(part[(size_t)i*256 + DD + col]);
  }
  __shared__ float ls[256], lq[256];
  ls[t] = s; lq[t] = q; __syncthreads();
  for (int o2=128; o2>0; o2>>=1){
    if (t < o2){ ls[t] += ls[t+o2]; lq[t] += lq[t+o2]; }
    __syncthreads();
  }
  if (t == 0){
    float mean = ls[0]*inv_n;
    float var  = lq[0]*inv_n - mean*mean;
    float sc = g[col]*rsqrtf(var + 1e-5f);
    ss[col]      = sc;
    ss[DD + col] = b[col] - mean*sc;
  }
}

// ---------------- in-place BN apply (h3 only): x = x*scale + shift ----------------
__global__ __launch_bounds__(256) void bn_apply(
    float* __restrict__ x, size_t rows, const float* __restrict__ ss){
  size_t id = (size_t)blockIdx.x*256 + threadIdx.x;
  size_t total = rows*32;
  if (id >= total) return;
  float4* p = (float4*)x + id;
  int c = (int)(id & 31) * 4;
  float4 v = *p;
  v.x = v.x*ss[c]   + ss[DD+c];
  v.y = v.y*ss[c+1] + ss[DD+c+1];
  v.z = v.z*ss[c+2] + ss[DD+c+2];
  v.w = v.w*ss[c+3] + ss[DD+c+3];
  *p = v;
}

extern "C" void kernel_launch(void* const* d_in, const int* in_sizes, int n_in,
                              void* d_out, int out_size, void* d_ws, size_t ws_size,
                              hipStream_t stream){
  const float* h   = (const float*)d_in[0];
  const float* e   = (const float*)d_in[1];
  const int*   src = (const int*)d_in[2];
  const int*   dst = (const int*)d_in[3];
  const float* Wq  = (const float*)d_in[4];
  const float* Wk  = (const float*)d_in[5];
  const float* Wv  = (const float*)d_in[6];
  const float* We  = (const float*)d_in[7];
  const float* Wo  = (const float*)d_in[8];
  const float* bo  = (const float*)d_in[9];
  const float* g1h = (const float*)d_in[10];
  const float* b1h = (const float*)d_in[11];
  const float* g1e = (const float*)d_in[12];
  const float* b1e = (const float*)d_in[13];
  const float* W1  = (const float*)d_in[14];
  const float* b1  = (const float*)d_in[15];
  const float* W2  = (const float*)d_in[16];
  const float* b2  = (const float*)d_in[17];
  const float* g2h = (const float*)d_in[18];
  const float* b2h = (const float*)d_in[19];

  float* out = (float*)d_out;
  float* h3  = out;                       // [NN][128]
  float* e2  = out + (size_t)NN*DD;       // [NEDGE][128]

  char* ws = (char*)d_ws;
  size_t off_b = 0;
  auto take = [&](size_t bytes)->char*{
    char* p = ws + off_b; off_b = (off_b + bytes + 255) & ~(size_t)255; return p;
  };
  short* wT     = (short*)take((size_t)147456*2);
  float* ssE    = (float*)take(256*4);
  float* ss1    = (float*)take(256*4);
  float* ss2    = (float*)take(256*4);
  short* QbP    = (short*)take((size_t)NN*DD*2);
  short* KbP    = (short*)take((size_t)NN*DD*2);
  short* Vb     = (short*)take((size_t)NN*DD*2);
  short* hA     = (short*)take((size_t)NN*DD*2);
  short* e2p    = (short*)take((size_t)NEDGE*DD*2);
  short* sArrB  = (short*)take((size_t)NEDGE*8*2);
  int*   cnt2   = (int*)take((size_t)2*NN*4);     // counts | cursor
  int*   counts = cnt2;
  int*   cursor = cnt2 + NN;
  int*   offs   = (int*)take((size_t)(NN+1)*4);
  int*   perm   = (int*)take((size_t)NEDGE*4);
  short* h2pre  = (short*)take((size_t)NN*DD*2);
  short* ffn1   = (short*)take((size_t)NN*256*2);
  short* partEB = (short*)take((size_t)32000*256*2);
  float* partH2 = (float*)take((size_t)782*256*4);
  float* partH3 = (float*)take((size_t)782*256*4);

  hipMemsetAsync(cnt2, 0, (size_t)2*NN*4, stream);

  prep_hist<<<2576,256,0,stream>>>(Wq,Wk,Wv,We,Wo,W1,W2,wT, dst, counts);
  scan_counts<<<1,256,0,stream>>>(counts, offs);
  qkv_scatter<<<2782,256,0,stream>>>(h, wT, QbP, KbP, Vb, dst, offs, cursor, perm);
  edge_fused<<<8000,256,0,stream>>>(e, wT+49152, QbP, KbP, src, dst,
                                    e2p, sArrB, partEB);
  bn_reduce_bf16<<<128,256,0,stream>>>(partEB, 32000, 1.f/(float)NEDGE, g1e, b1e, ssE);
  agg_bn<<<14548,256,0,stream>>>(offs, perm, src, sArrB, Vb, hA, e2p, ssE, e2);
  attn_out<<<782,256,0,stream>>>(hA, wT+65536, bo, h, h2pre, partH2);
  bn_reduce<<<128,256,0,stream>>>(partH2, 782, 1.f/(float)NN, g1h, b1h, ss1);
  ffn1_gemm<<<782,256,0,stream>>>(h2pre, ss1, wT+81920, b1, ffn1);
  ffn2_gemm<<<782,256,0,stream>>>(ffn1, wT+114688, b2, h2pre, ss1, h3, partH3);
  bn_reduce<<<128,256,0,stream>>>(partH3, 782, 1.f/(float)NN, g2h, b2h, ss2);
  bn_apply<<<6250,256,0,stream>>>(h3, (size_t)NN, ss2);
}

// Round 9
// 674.940 us; speedup vs baseline: 1.6347x; 1.3126x over previous
//
#include <hip/hip_runtime.h>
#include <math.h>

#define NN 50000
#define NEDGE 512000
#define DD 128

typedef short bf16x8 __attribute__((ext_vector_type(8)));
typedef float f32x4 __attribute__((ext_vector_type(4)));

__device__ __forceinline__ short f2bf(float f){
  union { float f; unsigned u; } v; v.f = f;
  unsigned u = v.u;
  return (short)((u + 0x7fffu + ((u >> 16) & 1u)) >> 16);
}
__device__ __forceinline__ float bf2f(short s){
  union { unsigned u; float f; } v; v.u = ((unsigned)(unsigned short)s) << 16; return v.f;
}

__device__ __forceinline__ bf16x8 packA(const float* __restrict__ rowp, int kbase){
  float4 x = *(const float4*)(rowp + kbase);
  float4 y = *(const float4*)(rowp + kbase + 4);
  bf16x8 r;
  r[0]=f2bf(x.x); r[1]=f2bf(x.y); r[2]=f2bf(x.z); r[3]=f2bf(x.w);
  r[4]=f2bf(y.x); r[5]=f2bf(y.y); r[6]=f2bf(y.z); r[7]=f2bf(y.w);
  return r;
}

// ------- kernel A: prep_w (blocks 0..575) + hist_dst (blocks 576..2575) -------
__global__ __launch_bounds__(256) void prep_hist(
    const float* __restrict__ Wq, const float* __restrict__ Wk,
    const float* __restrict__ Wv, const float* __restrict__ We,
    const float* __restrict__ Wo, const float* __restrict__ W1,
    const float* __restrict__ W2, short* __restrict__ wdst,
    const int* __restrict__ dst, int* __restrict__ counts){
  if (blockIdx.x >= 576){
    int id = (blockIdx.x-576)*256 + threadIdx.x;
    if (id < NEDGE) atomicAdd(&counts[dst[id]], 1);
    return;
  }
  int id = blockIdx.x*256 + threadIdx.x;
  const float* src; short* dstp; int K, NCOL, local;
  if (id < 81920){
    int m = id >> 14; local = id & 16383; K = 128; NCOL = 128;
    src = (m==0)?Wq:(m==1)?Wk:(m==2)?Wv:(m==3)?We:Wo;
    dstp = wdst + m*16384;
  } else if (id < 114688){
    local = id - 81920; K = 128; NCOL = 256; src = W1; dstp = wdst + 81920;
  } else if (id < 147456){
    local = id - 114688; K = 256; NCOL = 128; src = W2; dstp = wdst + 114688;
  } else return;
  int k = local / NCOL, n = local % NCOL;
  dstp[n*K + k] = f2bf(src[local]);
}

// ------- parallel scan (3 small kernels instead of one 1-block kernel) -------
#define SCAN_NB 196
__global__ __launch_bounds__(256) void scan_p1(
    const int* __restrict__ counts, int* __restrict__ bsum){
  int idx = blockIdx.x*256 + threadIdx.x;
  int v = (idx < NN) ? counts[idx] : 0;
  __shared__ int sd[256];
  sd[threadIdx.x] = v; __syncthreads();
  for (int o=128;o>0;o>>=1){
    if (threadIdx.x < o) sd[threadIdx.x] += sd[threadIdx.x+o];
    __syncthreads();
  }
  if (threadIdx.x == 0) bsum[blockIdx.x] = sd[0];
}
__global__ __launch_bounds__(256) void scan_p2(
    const int* __restrict__ bsum, int* __restrict__ bbase){
  int t = threadIdx.x;
  int v = (t < SCAN_NB) ? bsum[t] : 0;
  __shared__ int ps[256];
  ps[t] = v; __syncthreads();
  for (int o=1;o<256;o<<=1){
    int x = (t>=o) ? ps[t-o] : 0;
    __syncthreads();
    ps[t] += x;
    __syncthreads();
  }
  if (t < SCAN_NB) bbase[t] = ps[t] - v;   // exclusive
}
__global__ __launch_bounds__(256) void scan_p3(
    const int* __restrict__ counts, const int* __restrict__ bbase,
    int* __restrict__ off){
  int t = threadIdx.x;
  int idx = blockIdx.x*256 + t;
  int v = (idx < NN) ? counts[idx] : 0;
  __shared__ int ps[256];
  ps[t] = v; __syncthreads();
  for (int o=1;o<256;o<<=1){
    int x = (t>=o) ? ps[t-o] : 0;
    __syncthreads();
    ps[t] += x;
    __syncthreads();
  }
  if (idx < NN) off[idx] = bbase[blockIdx.x] + ps[t] - v;
  if (blockIdx.x == 0 && t == 0) off[NN] = NEDGE;
}

// ------- kernel B: qkv_gemm (blocks 0..781) + scatter_perm (rest) -------
// K and Q stored PERMUTED: XbP[node*128 + c*8 + j] = X[node][j*16+c].
__global__ __launch_bounds__(256) void qkv_scatter(
    const float* __restrict__ h, const short* __restrict__ wT,
    short* __restrict__ QbP, short* __restrict__ KbP, short* __restrict__ Vb,
    const int* __restrict__ dst, const int* __restrict__ off,
    int* __restrict__ cursor, int* __restrict__ perm){
  if (blockIdx.x >= 782){
    int id = (blockIdx.x-782)*256 + threadIdx.x;
    if (id < NEDGE){
      int d = dst[id];
      int r = atomicAdd(&cursor[d], 1);
      perm[off[d] + r] = id;
    }
    return;
  }
  const short* WqT = wT;
  const short* WkT = wT + 16384;
  const short* WvT = wT + 32768;
  int lane = threadIdx.x & 63, wave = threadIdx.x >> 6;
  int r16 = lane & 15, kg = lane >> 4;
  int rowbase = blockIdx.x*64 + wave*16;
  int arow = rowbase + r16; if (arow > NN-1) arow = NN-1;
  const float* Arow = h + (size_t)arow*DD;
  f32x4 acc[3][8];
  #pragma unroll
  for (int m=0;m<3;m++)
    #pragma unroll
    for (int j=0;j<8;j++) acc[m][j] = (f32x4){0.f,0.f,0.f,0.f};
  #pragma unroll
  for (int kc=0;kc<4;kc++){
    int kb = kc*32 + kg*8;
    bf16x8 a = packA(Arow, kb);
    #pragma unroll
    for (int j=0;j<8;j++){
      bf16x8 bq = *(const bf16x8*)(WqT + (j*16+r16)*DD + kb);
      acc[0][j] = __builtin_amdgcn_mfma_f32_16x16x32_bf16(a, bq, acc[0][j], 0,0,0);
      bf16x8 bk = *(const bf16x8*)(WkT + (j*16+r16)*DD + kb);
      acc[1][j] = __builtin_amdgcn_mfma_f32_16x16x32_bf16(a, bk, acc[1][j], 0,0,0);
      bf16x8 bv = *(const bf16x8*)(WvT + (j*16+r16)*DD + kb);
      acc[2][j] = __builtin_amdgcn_mfma_f32_16x16x32_bf16(a, bv, acc[2][j], 0,0,0);
    }
  }
  int orow0 = rowbase + kg*4;
  #pragma unroll
  for (int j=0;j<8;j++){
    #pragma unroll
    for (int r=0;r<4;r++){
      int row = orow0 + r;
      if (row < NN){
        QbP[(size_t)row*DD + r16*8 + j] = f2bf(acc[0][j][r]);   // permuted
        KbP[(size_t)row*DD + r16*8 + j] = f2bf(acc[1][j][r]);   // permuted
        Vb [(size_t)row*DD + j*16 + r16] = f2bf(acc[2][j][r]);  // natural
      }
    }
  }
}

// -------- edge pass: BARRIER-FREE. Each wave stages its own 16 rows of e
//   into its private LDS slice, runs MFMA from it, stats via shfl -> global
//   bf16 partials, in-register scores, coalesced bf16 copy-out. --------
__global__ __launch_bounds__(256) void edge_fused(
    const float* __restrict__ e, const short* __restrict__ WeT,
    const short* __restrict__ QbP, const short* __restrict__ KbP,
    const int* __restrict__ src, const int* __restrict__ dst,
    short* __restrict__ e2p, short* __restrict__ sArrB,
    short* __restrict__ partB){
  __shared__ short eL[64*128];    // 16KB; rows [w*16,w*16+16) private to wave w
  int tid = threadIdx.x;
  int rowbase = blockIdx.x*64;
  int lane = tid & 63, wave = tid >> 6;
  int c = lane & 15, kg = lane >> 4;
  // ---- issue score-phase K/Q loads FIRST (8 independent 16B vectors) ----
  bf16x8 kv[4], qv[4];
  #pragma unroll
  for (int r=0;r<4;r++){
    int ed = rowbase + wave*16 + kg*4 + r;
    int sj = src[ed], dj = dst[ed];
    kv[r] = *(const bf16x8*)(KbP + (size_t)sj*DD + c*8);
    qv[r] = *(const bf16x8*)(QbP + (size_t)dj*DD + c*8);
  }
  // ---- stage own wave's 16 rows: fp32 -> bf16 LDS (swizzled granules) ----
  {
    int row = wave*16 + (lane >> 2);
    int c0  = (lane & 3) * 32;
    const float* rp = e + (size_t)(rowbase+row)*DD + c0;
    #pragma unroll
    for (int g=0; g<4; ++g){
      float4 x = *(const float4*)(rp + g*8);
      float4 y = *(const float4*)(rp + g*8 + 4);
      bf16x8 v;
      v[0]=f2bf(x.x); v[1]=f2bf(x.y); v[2]=f2bf(x.z); v[3]=f2bf(x.w);
      v[4]=f2bf(y.x); v[5]=f2bf(y.y); v[6]=f2bf(y.z); v[7]=f2bf(y.w);
      int col8 = (c0 >> 3) + g;
      *(bf16x8*)&eL[row*DD + ((col8 ^ (row&7))<<3)] = v;
    }
  }
  // (no __syncthreads: all LDS traffic is wave-private, lgkmcnt orders it)
  // ---- MFMA: A from LDS (own wave's 16 rows), B = WeT (L2-resident) ----
  f32x4 acc[8];
  #pragma unroll
  for (int j=0;j<8;j++) acc[j] = (f32x4){0.f,0.f,0.f,0.f};
  int arow = wave*16 + c;
  #pragma unroll
  for (int kc=0;kc<4;kc++){
    int col8 = kc*4 + kg;
    bf16x8 a = *(const bf16x8*)&eL[arow*DD + ((col8 ^ (arow&7))<<3)];
    int kb = kc*32 + kg*8;
    #pragma unroll
    for (int j=0;j<8;j++){
      bf16x8 b = *(const bf16x8*)(WeT + (j*16+c)*DD + kb);
      acc[j] = __builtin_amdgcn_mfma_f32_16x16x32_bf16(a, b, acc[j], 0,0,0);
    }
  }
  // ---- stats + in-place v = e + Eh (wave-private rows) ----
  float ssum[8], ssq[8];
  #pragma unroll
  for (int j=0;j<8;j++){ ssum[j]=0.f; ssq[j]=0.f; }
  #pragma unroll
  for (int r=0;r<4;r++){
    int le = wave*16 + kg*4 + r;
    int sw = le & 7;
    int rowoff = le*DD;
    #pragma unroll
    for (int j=0;j<8;j++){
      int col = j*16 + c;
      int sidx = rowoff + (((col>>3) ^ sw)<<3) + (col & 7);
      float v = bf2f(eL[sidx]) + acc[j][r];
      eL[sidx] = f2bf(v);
      ssum[j] += v; ssq[j] += v*v;
    }
  }
  #pragma unroll
  for (int j=0;j<8;j++){
    ssum[j] += __shfl_xor(ssum[j],16); ssum[j] += __shfl_xor(ssum[j],32);
    ssq[j]  += __shfl_xor(ssq[j],16);  ssq[j]  += __shfl_xor(ssq[j],32);
  }
  if (kg == 0){
    size_t pb = ((size_t)blockIdx.x*4 + wave)*256;
    #pragma unroll
    for (int j=0;j<8;j++){
      partB[pb + j*16 + c]       = f2bf(ssum[j]);
      partB[pb + 128 + j*16 + c] = f2bf(ssq[j]);
    }
  }
  // ---- scores: lane c holds K/Q slice (8 heads); reduce over 16 lanes ----
  #pragma unroll
  for (int r=0;r<4;r++){
    int ed = rowbase + wave*16 + kg*4 + r;
    float sreg = 0.f;
    #pragma unroll
    for (int j=0;j<8;j++){
      float p = bf2f(kv[r][j]) * bf2f(qv[r][j]) * acc[j][r];
      p += __shfl_xor(p,1); p += __shfl_xor(p,2);
      p += __shfl_xor(p,4); p += __shfl_xor(p,8);
      if (c == j) sreg = p;
    }
    if (c < 8){
      float s = __expf(fminf(fmaxf(sreg*0.25f,-5.f),5.f));
      sArrB[(size_t)ed*8 + c] = f2bf(s);
    }
  }
  // ---- copy-out e2pre bf16 (wave-local rows, 16B/lane coalesced) ----
  #pragma unroll
  for (int it=0; it<4; ++it){
    int row = wave*16 + it*4 + (lane>>4);
    int col8 = lane & 15;
    bf16x8 v = *(const bf16x8*)&eL[row*DD + ((col8 ^ (row&7))<<3)];
    *(bf16x8*)(e2p + (size_t)(rowbase+row)*DD + col8*8) = v;
  }
}

// ------- merged: node aggregation (blocks 0..12499) + e2 BN stream (rest) -------
__global__ __launch_bounds__(256) void agg_bn(
    const int* __restrict__ off, const int* __restrict__ perm,
    const int* __restrict__ src, const short* __restrict__ sArrB,
    const short* __restrict__ Vb, short* __restrict__ hA,
    const short* __restrict__ e2p, const float* __restrict__ ssE,
    float* __restrict__ e2){
  if (blockIdx.x >= 12500){
    size_t gi0 = (size_t)(blockIdx.x-12500)*256 + threadIdx.x;
    int col0 = (int)(gi0 & 15) * 8;
    float scr[8], shr[8];
    #pragma unroll
    for (int i=0;i<8;i++){ scr[i]=ssE[col0+i]; shr[i]=ssE[DD+col0+i]; }
    size_t stride = (size_t)2048*256;
    size_t total = (size_t)NEDGE*16;
    for (size_t gi = gi0; gi < total; gi += stride){
      bf16x8 v = *(const bf16x8*)(e2p + gi*8);
      float4 o0, o1;
      o0.x = bf2f(v[0])*scr[0]+shr[0];
      o0.y = bf2f(v[1])*scr[1]+shr[1];
      o0.z = bf2f(v[2])*scr[2]+shr[2];
      o0.w = bf2f(v[3])*scr[3]+shr[3];
      o1.x = bf2f(v[4])*scr[4]+shr[4];
      o1.y = bf2f(v[5])*scr[5]+shr[5];
      o1.z = bf2f(v[6])*scr[6]+shr[6];
      o1.w = bf2f(v[7])*scr[7]+shr[7];
      *(float4*)(e2 + gi*8)     = o0;
      *(float4*)(e2 + gi*8 + 4) = o1;
    }
    return;
  }
  int wave = threadIdx.x >> 6, lane = threadIdx.x & 63;
  int node = blockIdx.x*4 + wave;
  if (node >= NN) return;
  int beg = off[node], end = off[node+1];
  int col2 = lane*2;
  int hd = lane >> 3;
  float w0 = 0.f, w1 = 0.f, zh = 0.f;
  int ed = beg;
  for (; ed+3 < end; ed += 4){
    int pe0 = perm[ed],   pe1 = perm[ed+1];
    int pe2 = perm[ed+2], pe3 = perm[ed+3];
    int sj0 = src[pe0], sj1 = src[pe1], sj2 = src[pe2], sj3 = src[pe3];
    float s0 = bf2f(sArrB[(size_t)pe0*8 + hd]);
    float s1 = bf2f(sArrB[(size_t)pe1*8 + hd]);
    float s2 = bf2f(sArrB[(size_t)pe2*8 + hd]);
    float s3 = bf2f(sArrB[(size_t)pe3*8 + hd]);
    unsigned v0 = *(const unsigned*)(Vb + (size_t)sj0*DD + col2);
    unsigned v1 = *(const unsigned*)(Vb + (size_t)sj1*DD + col2);
    unsigned v2 = *(const unsigned*)(Vb + (size_t)sj2*DD + col2);
    unsigned v3 = *(const unsigned*)(Vb + (size_t)sj3*DD + col2);
    w0 += bf2f((short)(v0 & 0xffff))*s0 + bf2f((short)(v1 & 0xffff))*s1
        + bf2f((short)(v2 & 0xffff))*s2 + bf2f((short)(v3 & 0xffff))*s3;
    w1 += bf2f((short)(v0 >> 16))*s0 + bf2f((short)(v1 >> 16))*s1
        + bf2f((short)(v2 >> 16))*s2 + bf2f((short)(v3 >> 16))*s3;
    zh += s0 + s1 + s2 + s3;
  }
  for (; ed < end; ++ed){
    int pe = perm[ed];
    int sj = src[pe];
    float s = bf2f(sArrB[(size_t)pe*8 + hd]);
    unsigned vv = *(const unsigned*)(Vb + (size_t)sj*DD + col2);
    w0 += bf2f((short)(vv & 0xffff)) * s;
    w1 += bf2f((short)(vv >> 16)) * s;
    zh += s;
  }
  float inv = 1.f/(zh + 1e-6f);
  unsigned outv = (((unsigned)(unsigned short)f2bf(w1*inv)) << 16)
                |  ((unsigned)(unsigned short)f2bf(w0*inv));
  *(unsigned*)(hA + (size_t)node*DD + col2) = outv;
}

// ---- h2pre(bf16) = hA @ Wo + bo + h; per-wave fp32 partials, no barriers ----
__global__ __launch_bounds__(256) void attn_out(
    const short* __restrict__ hA,
    const short* __restrict__ WoT, const float* __restrict__ bo,
    const float* __restrict__ h, short* __restrict__ h2pre,
    float* __restrict__ part){
  int lane = threadIdx.x & 63, wave = threadIdx.x >> 6;
  int r16 = lane & 15, kg = lane >> 4;
  int rowbase = blockIdx.x*64 + wave*16;
  int arow = rowbase + r16; if (arow > NN-1) arow = NN-1;
  const short* Arow = hA + (size_t)arow*DD;
  f32x4 acc[8];
  #pragma unroll
  for (int j=0;j<8;j++) acc[j] = (f32x4){0.f,0.f,0.f,0.f};
  #pragma unroll
  for (int kc=0;kc<4;kc++){
    int kb = kc*32 + kg*8;
    bf16x8 a = *(const bf16x8*)(Arow + kb);
    #pragma unroll
    for (int j=0;j<8;j++){
      bf16x8 b = *(const bf16x8*)(WoT + (j*16+r16)*DD + kb);
      acc[j] = __builtin_amdgcn_mfma_f32_16x16x32_bf16(a, b, acc[j], 0,0,0);
    }
  }
  int orow0 = rowbase + kg*4;
  float ssum[8], ssq[8];
  #pragma unroll
  for (int j=0;j<8;j++){ ssum[j]=0.f; ssq[j]=0.f; }
  #pragma unroll
  for (int j=0;j<8;j++){
    #pragma unroll
    for (int r=0;r<4;r++){
      int row = orow0 + r;
      if (row < NN){
        int col = j*16 + r16;
        float v = acc[j][r] + bo[col] + h[(size_t)row*DD + col];
        h2pre[(size_t)row*DD + col] = f2bf(v);
        ssum[j] += v; ssq[j] += v*v;
      }
    }
  }
  #pragma unroll
  for (int j=0;j<8;j++){
    ssum[j] += __shfl_xor(ssum[j],16); ssum[j] += __shfl_xor(ssum[j],32);
    ssq[j]  += __shfl_xor(ssq[j],16);  ssq[j]  += __shfl_xor(ssq[j],32);
  }
  if (kg == 0){
    size_t pb = ((size_t)blockIdx.x*4 + wave)*256;
    #pragma unroll
    for (int j=0;j<8;j++){
      part[pb + j*16 + r16]       = ssum[j];
      part[pb + 128 + j*16 + r16] = ssq[j];
    }
  }
}

// ---------------- FFN1: relu(BN1(h2pre) @ W1 + b1) -> bf16 ----------------
__global__ __launch_bounds__(256) void ffn1_gemm(
    const short* __restrict__ h2pre, const float* __restrict__ ss1,
    const short* __restrict__ W1T, const float* __restrict__ b1,
    short* __restrict__ ffn1){
  int lane = threadIdx.x & 63, wave = threadIdx.x >> 6;
  int r16 = lane & 15, kg = lane >> 4;
  int rowbase = blockIdx.x*64 + wave*16;
  int arow = rowbase + r16; if (arow > NN-1) arow = NN-1;
  const short* Arow = h2pre + (size_t)arow*DD;
  f32x4 acc[16];
  #pragma unroll
  for (int j=0;j<16;j++) acc[j] = (f32x4){0.f,0.f,0.f,0.f};
  #pragma unroll
  for (int kc=0;kc<4;kc++){
    int kb = kc*32 + kg*8;
    bf16x8 raw = *(const bf16x8*)(Arow + kb);
    float4 s0 = *(const float4*)(ss1 + kb);
    float4 s1 = *(const float4*)(ss1 + kb + 4);
    float4 t0 = *(const float4*)(ss1 + DD + kb);
    float4 t1 = *(const float4*)(ss1 + DD + kb + 4);
    bf16x8 a;
    a[0]=f2bf(bf2f(raw[0])*s0.x+t0.x); a[1]=f2bf(bf2f(raw[1])*s0.y+t0.y);
    a[2]=f2bf(bf2f(raw[2])*s0.z+t0.z); a[3]=f2bf(bf2f(raw[3])*s0.w+t0.w);
    a[4]=f2bf(bf2f(raw[4])*s1.x+t1.x); a[5]=f2bf(bf2f(raw[5])*s1.y+t1.y);
    a[6]=f2bf(bf2f(raw[6])*s1.z+t1.z); a[7]=f2bf(bf2f(raw[7])*s1.w+t1.w);
    #pragma unroll
    for (int j=0;j<16;j++){
      bf16x8 b = *(const bf16x8*)(W1T + (j*16+r16)*DD + kb);
      acc[j] = __builtin_amdgcn_mfma_f32_16x16x32_bf16(a, b, acc[j], 0,0,0);
    }
  }
  int orow0 = rowbase + kg*4;
  #pragma unroll
  for (int j=0;j<16;j++){
    #pragma unroll
    for (int r=0;r<4;r++){
      int row = orow0 + r;
      if (row < NN){
        int col = j*16 + r16;
        float v = fmaxf(acc[j][r] + b1[col], 0.f);
        ffn1[(size_t)row*256 + col] = f2bf(v);
      }
    }
  }
}

// ---- FFN2: h3pre = BN1(h2pre) + ffn1 @ W2 + b2; per-wave partials ----
__global__ __launch_bounds__(256) void ffn2_gemm(
    const short* __restrict__ ffn1, const short* __restrict__ W2T,
    const float* __restrict__ b2, const short* __restrict__ h2pre,
    const float* __restrict__ ss1, float* __restrict__ h3pre,
    float* __restrict__ part){
  int lane = threadIdx.x & 63, wave = threadIdx.x >> 6;
  int r16 = lane & 15, kg = lane >> 4;
  int rowbase = blockIdx.x*64 + wave*16;
  int arow = rowbase + r16; if (arow > NN-1) arow = NN-1;
  const short* Arow = ffn1 + (size_t)arow*256;
  f32x4 acc[8];
  #pragma unroll
  for (int j=0;j<8;j++) acc[j] = (f32x4){0.f,0.f,0.f,0.f};
  #pragma unroll
  for (int kc=0;kc<8;kc++){
    int kb = kc*32 + kg*8;
    bf16x8 a = *(const bf16x8*)(Arow + kb);
    #pragma unroll
    for (int j=0;j<8;j++){
      bf16x8 b = *(const bf16x8*)(W2T + (j*16+r16)*256 + kb);
      acc[j] = __builtin_amdgcn_mfma_f32_16x16x32_bf16(a, b, acc[j], 0,0,0);
    }
  }
  int orow0 = rowbase + kg*4;
  float ssum[8], ssq[8];
  #pragma unroll
  for (int j=0;j<8;j++){ ssum[j]=0.f; ssq[j]=0.f; }
  #pragma unroll
  for (int j=0;j<8;j++){
    #pragma unroll
    for (int r=0;r<4;r++){
      int row = orow0 + r;
      if (row < NN){
        int col = j*16 + r16;
        float x = bf2f(h2pre[(size_t)row*DD + col]);
        float h2bn = x*ss1[col] + ss1[DD+col];
        float v = h2bn + acc[j][r] + b2[col];
        h3pre[(size_t)row*DD + col] = v;
        ssum[j] += v; ssq[j] += v*v;
      }
    }
  }
  #pragma unroll
  for (int j=0;j<8;j++){
    ssum[j] += __shfl_xor(ssum[j],16); ssum[j] += __shfl_xor(ssum[j],32);
    ssq[j]  += __shfl_xor(ssq[j],16);  ssq[j]  += __shfl_xor(ssq[j],32);
  }
  if (kg == 0){
    size_t pb = ((size_t)blockIdx.x*4 + wave)*256;
    #pragma unroll
    for (int j=0;j<8;j++){
      part[pb + j*16 + r16]       = ssum[j];
      part[pb + 128 + j*16 + r16] = ssq[j];
    }
  }
}

// ---------------- BN stats reduce (fp32 partials) ----------------
__global__ __launch_bounds__(256) void bn_reduce(
    const float* __restrict__ part, int nparts, float inv_n,
    const float* __restrict__ g, const float* __restrict__ b,
    float* __restrict__ ss){
  int col = blockIdx.x, t = threadIdx.x;
  float s = 0.f, q = 0.f;
  for (int i=t; i<nparts; i+=256){
    s += part[(size_t)i*256 + col];
    q += part[(size_t)i*256 + DD + col];
  }
  __shared__ float ls[256], lq[256];
  ls[t] = s; lq[t] = q; __syncthreads();
  for (int o2=128; o2>0; o2>>=1){
    if (t < o2){ ls[t] += ls[t+o2]; lq[t] += lq[t+o2]; }
    __syncthreads();
  }
  if (t == 0){
    float mean = ls[0]*inv_n;
    float var  = lq[0]*inv_n - mean*mean;
    float sc = g[col]*rsqrtf(var + 1e-5f);
    ss[col]      = sc;
    ss[DD + col] = b[col] - mean*sc;
  }
}

// ---------------- BN stats reduce (bf16 partials) ----------------
__global__ __launch_bounds__(256) void bn_reduce_bf16(
    const short* __restrict__ part, int nparts, float inv_n,
    const float* __restrict__ g, const float* __restrict__ b,
    float* __restrict__ ss){
  int col = blockIdx.x, t = threadIdx.x;
  float s = 0.f, q = 0.f;
  for (int i=t; i<nparts; i+=256){
    s += bf2f(part[(size_t)i*256 + col]);
    q += bf2f(part[(size_t)i*256 + DD + col]);
  }
  __shared__ float ls[256], lq[256];
  ls[t] = s; lq[t] = q; __syncthreads();
  for (int o2=128; o2>0; o2>>=1){
    if (t < o2){ ls[t] += ls[t+o2]; lq[t] += lq[t+o2]; }
    __syncthreads();
  }
  if (t == 0){
    float mean = ls[0]*inv_n;
    float var  = lq[0]*inv_n - mean*mean;
    float sc = g[col]*rsqrtf(var + 1e-5f);
    ss[col]      = sc;
    ss[DD + col] = b[col] - mean*sc;
  }
}

// ---------------- in-place BN apply (h3 only) ----------------
__global__ __launch_bounds__(256) void bn_apply(
    float* __restrict__ x, size_t rows, const float* __restrict__ ss){
  size_t id = (size_t)blockIdx.x*256 + threadIdx.x;
  size_t total = rows*32;
  if (id >= total) return;
  float4* p = (float4*)x + id;
  int c = (int)(id & 31) * 4;
  float4 v = *p;
  v.x = v.x*ss[c]   + ss[DD+c];
  v.y = v.y*ss[c+1] + ss[DD+c+1];
  v.z = v.z*ss[c+2] + ss[DD+c+2];
  v.w = v.w*ss[c+3] + ss[DD+c+3];
  *p = v;
}

extern "C" void kernel_launch(void* const* d_in, const int* in_sizes, int n_in,
                              void* d_out, int out_size, void* d_ws, size_t ws_size,
                              hipStream_t stream){
  const float* h   = (const float*)d_in[0];
  const float* e   = (const float*)d_in[1];
  const int*   src = (const int*)d_in[2];
  const int*   dst = (const int*)d_in[3];
  const float* Wq  = (const float*)d_in[4];
  const float* Wk  = (const float*)d_in[5];
  const float* Wv  = (const float*)d_in[6];
  const float* We  = (const float*)d_in[7];
  const float* Wo  = (const float*)d_in[8];
  const float* bo  = (const float*)d_in[9];
  const float* g1h = (const float*)d_in[10];
  const float* b1h = (const float*)d_in[11];
  const float* g1e = (const float*)d_in[12];
  const float* b1e = (const float*)d_in[13];
  const float* W1  = (const float*)d_in[14];
  const float* b1  = (const float*)d_in[15];
  const float* W2  = (const float*)d_in[16];
  const float* b2  = (const float*)d_in[17];
  const float* g2h = (const float*)d_in[18];
  const float* b2h = (const float*)d_in[19];

  float* out = (float*)d_out;
  float* h3  = out;                       // [NN][128]
  float* e2  = out + (size_t)NN*DD;       // [NEDGE][128]

  char* ws = (char*)d_ws;
  size_t off_b = 0;
  auto take = [&](size_t bytes)->char*{
    char* p = ws + off_b; off_b = (off_b + bytes + 255) & ~(size_t)255; return p;
  };
  short* wT     = (short*)take((size_t)147456*2);
  float* ssE    = (float*)take(256*4);
  float* ss1    = (float*)take(256*4);
  float* ss2    = (float*)take(256*4);
  short* QbP    = (short*)take((size_t)NN*DD*2);
  short* KbP    = (short*)take((size_t)NN*DD*2);
  short* Vb     = (short*)take((size_t)NN*DD*2);
  short* hA     = (short*)take((size_t)NN*DD*2);
  short* e2p    = (short*)take((size_t)NEDGE*DD*2);
  short* sArrB  = (short*)take((size_t)NEDGE*8*2);
  int*   cnt2   = (int*)take((size_t)2*NN*4);     // counts | cursor
  int*   counts = cnt2;
  int*   cursor = cnt2 + NN;
  int*   offs   = (int*)take((size_t)(NN+1)*4);
  int*   perm   = (int*)take((size_t)NEDGE*4);
  int*   bsum   = (int*)take((size_t)256*4);
  int*   bbase  = (int*)take((size_t)256*4);
  short* h2pre  = (short*)take((size_t)NN*DD*2);
  short* ffn1   = (short*)take((size_t)NN*256*2);
  short* partEB = (short*)take((size_t)32000*256*2);
  float* partH2 = (float*)take((size_t)3128*256*4);
  float* partH3 = (float*)take((size_t)3128*256*4);

  hipMemsetAsync(cnt2, 0, (size_t)2*NN*4, stream);

  prep_hist<<<2576,256,0,stream>>>(Wq,Wk,Wv,We,Wo,W1,W2,wT, dst, counts);
  scan_p1<<<SCAN_NB,256,0,stream>>>(counts, bsum);
  scan_p2<<<1,256,0,stream>>>(bsum, bbase);
  scan_p3<<<SCAN_NB,256,0,stream>>>(counts, bbase, offs);
  qkv_scatter<<<2782,256,0,stream>>>(h, wT, QbP, KbP, Vb, dst, offs, cursor, perm);
  edge_fused<<<8000,256,0,stream>>>(e, wT+49152, QbP, KbP, src, dst,
                                    e2p, sArrB, partEB);
  bn_reduce_bf16<<<128,256,0,stream>>>(partEB, 32000, 1.f/(float)NEDGE, g1e, b1e, ssE);
  agg_bn<<<14548,256,0,stream>>>(offs, perm, src, sArrB, Vb, hA, e2p, ssE, e2);
  attn_out<<<782,256,0,stream>>>(hA, wT+65536, bo, h, h2pre, partH2);
  bn_reduce<<<128,256,0,stream>>>(partH2, 3128, 1.f/(float)NN, g1h, b1h, ss1);
  ffn1_gemm<<<782,256,0,stream>>>(h2pre, ss1, wT+81920, b1, ffn1);
  ffn2_gemm<<<782,256,0,stream>>>(ffn1, wT+114688, b2, h2pre, ss1, h3, partH3);
  bn_reduce<<<128,256,0,stream>>>(partH3, 3128, 1.f/(float)NN, g2h, b2h, ss2);
  bn_apply<<<6250,256,0,stream>>>(h3, (size_t)NN, ss2);
}

// Round 10
// 668.031 us; speedup vs baseline: 1.6516x; 1.0103x over previous
//
#include <hip/hip_runtime.h>
#include <math.h>

#define NN 50000
#define NEDGE 512000
#define DD 128

typedef short bf16x8 __attribute__((ext_vector_type(8)));
typedef float f32x4 __attribute__((ext_vector_type(4)));

__device__ __forceinline__ short f2bf(float f){
  union { float f; unsigned u; } v; v.f = f;
  unsigned u = v.u;
  return (short)((u + 0x7fffu + ((u >> 16) & 1u)) >> 16);
}
__device__ __forceinline__ float bf2f(short s){
  union { unsigned u; float f; } v; v.u = ((unsigned)(unsigned short)s) << 16; return v.f;
}

__device__ __forceinline__ bf16x8 packA(const float* __restrict__ rowp, int kbase){
  float4 x = *(const float4*)(rowp + kbase);
  float4 y = *(const float4*)(rowp + kbase + 4);
  bf16x8 r;
  r[0]=f2bf(x.x); r[1]=f2bf(x.y); r[2]=f2bf(x.z); r[3]=f2bf(x.w);
  r[4]=f2bf(y.x); r[5]=f2bf(y.y); r[6]=f2bf(y.z); r[7]=f2bf(y.w);
  return r;
}

// ------- kernel A: prep_w (blocks 0..575) + hist_dst (blocks 576..2575) -------
__global__ __launch_bounds__(256) void prep_hist(
    const float* __restrict__ Wq, const float* __restrict__ Wk,
    const float* __restrict__ Wv, const float* __restrict__ We,
    const float* __restrict__ Wo, const float* __restrict__ W1,
    const float* __restrict__ W2, short* __restrict__ wdst,
    const int* __restrict__ dst, int* __restrict__ counts){
  if (blockIdx.x >= 576){
    int id = (blockIdx.x-576)*256 + threadIdx.x;
    if (id < NEDGE) atomicAdd(&counts[dst[id]], 1);
    return;
  }
  int id = blockIdx.x*256 + threadIdx.x;
  const float* src; short* dstp; int K, NCOL, local;
  if (id < 81920){
    int m = id >> 14; local = id & 16383; K = 128; NCOL = 128;
    src = (m==0)?Wq:(m==1)?Wk:(m==2)?Wv:(m==3)?We:Wo;
    dstp = wdst + m*16384;
  } else if (id < 114688){
    local = id - 81920; K = 128; NCOL = 256; src = W1; dstp = wdst + 81920;
  } else if (id < 147456){
    local = id - 114688; K = 256; NCOL = 128; src = W2; dstp = wdst + 114688;
  } else return;
  int k = local / NCOL, n = local % NCOL;
  dstp[n*K + k] = f2bf(src[local]);
}

// ------- parallel scan (3 small kernels) -------
#define SCAN_NB 196
__global__ __launch_bounds__(256) void scan_p1(
    const int* __restrict__ counts, int* __restrict__ bsum){
  int idx = blockIdx.x*256 + threadIdx.x;
  int v = (idx < NN) ? counts[idx] : 0;
  __shared__ int sd[256];
  sd[threadIdx.x] = v; __syncthreads();
  for (int o=128;o>0;o>>=1){
    if (threadIdx.x < o) sd[threadIdx.x] += sd[threadIdx.x+o];
    __syncthreads();
  }
  if (threadIdx.x == 0) bsum[blockIdx.x] = sd[0];
}
__global__ __launch_bounds__(256) void scan_p2(
    const int* __restrict__ bsum, int* __restrict__ bbase){
  int t = threadIdx.x;
  int v = (t < SCAN_NB) ? bsum[t] : 0;
  __shared__ int ps[256];
  ps[t] = v; __syncthreads();
  for (int o=1;o<256;o<<=1){
    int x = (t>=o) ? ps[t-o] : 0;
    __syncthreads();
    ps[t] += x;
    __syncthreads();
  }
  if (t < SCAN_NB) bbase[t] = ps[t] - v;   // exclusive
}
__global__ __launch_bounds__(256) void scan_p3(
    const int* __restrict__ counts, const int* __restrict__ bbase,
    int* __restrict__ off){
  int t = threadIdx.x;
  int idx = blockIdx.x*256 + t;
  int v = (idx < NN) ? counts[idx] : 0;
  __shared__ int ps[256];
  ps[t] = v; __syncthreads();
  for (int o=1;o<256;o<<=1){
    int x = (t>=o) ? ps[t-o] : 0;
    __syncthreads();
    ps[t] += x;
    __syncthreads();
  }
  if (idx < NN) off[idx] = bbase[blockIdx.x] + ps[t] - v;
  if (blockIdx.x == 0 && t == 0) off[NN] = NEDGE;
}

// ------- kernel B: qkv_gemm (blocks 0..781) + scatter (rest) -------
// K,Q PERMUTED: XbP[node*128 + c*8 + j] = X[node][j*16+c].  V natural.
// Scatter writes invpos[id] = CSR position, srcS[pos] = src[id].
__global__ __launch_bounds__(256) void qkv_scatter(
    const float* __restrict__ h, const short* __restrict__ wT,
    short* __restrict__ QbP, short* __restrict__ KbP, short* __restrict__ Vb,
    const int* __restrict__ src, const int* __restrict__ dst,
    const int* __restrict__ off, int* __restrict__ cursor,
    int* __restrict__ invpos, int* __restrict__ srcS){
  if (blockIdx.x >= 782){
    int id = (blockIdx.x-782)*256 + threadIdx.x;
    if (id < NEDGE){
      int d = dst[id];
      int r = atomicAdd(&cursor[d], 1);
      int pos = off[d] + r;
      invpos[id] = pos;
      srcS[pos] = src[id];
    }
    return;
  }
  const short* WqT = wT;
  const short* WkT = wT + 16384;
  const short* WvT = wT + 32768;
  int lane = threadIdx.x & 63, wave = threadIdx.x >> 6;
  int r16 = lane & 15, kg = lane >> 4;
  int rowbase = blockIdx.x*64 + wave*16;
  int arow = rowbase + r16; if (arow > NN-1) arow = NN-1;
  const float* Arow = h + (size_t)arow*DD;
  f32x4 acc[3][8];
  #pragma unroll
  for (int m=0;m<3;m++)
    #pragma unroll
    for (int j=0;j<8;j++) acc[m][j] = (f32x4){0.f,0.f,0.f,0.f};
  #pragma unroll
  for (int kc=0;kc<4;kc++){
    int kb = kc*32 + kg*8;
    bf16x8 a = packA(Arow, kb);
    #pragma unroll
    for (int j=0;j<8;j++){
      bf16x8 bq = *(const bf16x8*)(WqT + (j*16+r16)*DD + kb);
      acc[0][j] = __builtin_amdgcn_mfma_f32_16x16x32_bf16(a, bq, acc[0][j], 0,0,0);
      bf16x8 bk = *(const bf16x8*)(WkT + (j*16+r16)*DD + kb);
      acc[1][j] = __builtin_amdgcn_mfma_f32_16x16x32_bf16(a, bk, acc[1][j], 0,0,0);
      bf16x8 bv = *(const bf16x8*)(WvT + (j*16+r16)*DD + kb);
      acc[2][j] = __builtin_amdgcn_mfma_f32_16x16x32_bf16(a, bv, acc[2][j], 0,0,0);
    }
  }
  int orow0 = rowbase + kg*4;
  #pragma unroll
  for (int j=0;j<8;j++){
    #pragma unroll
    for (int r=0;r<4;r++){
      int row = orow0 + r;
      if (row < NN){
        QbP[(size_t)row*DD + r16*8 + j] = f2bf(acc[0][j][r]);   // permuted
        KbP[(size_t)row*DD + r16*8 + j] = f2bf(acc[1][j][r]);   // permuted
        Vb [(size_t)row*DD + j*16 + r16] = f2bf(acc[2][j][r]);  // natural
      }
    }
  }
}

// -------- edge pass: barrier-free, wave-private LDS slices; scores via
//   register-folding butterfly (15 shfl/edge) scattered to CSR-sorted sS. ----
__global__ __launch_bounds__(256) void edge_fused(
    const float* __restrict__ e, const short* __restrict__ WeT,
    const short* __restrict__ QbP, const short* __restrict__ KbP,
    const int* __restrict__ src, const int* __restrict__ dst,
    const int* __restrict__ invpos,
    short* __restrict__ e2p, short* __restrict__ sS,
    short* __restrict__ partB){
  __shared__ short eL[64*128];    // 16KB; rows [w*16,w*16+16) private to wave w
  int tid = threadIdx.x;
  int rowbase = blockIdx.x*64;
  int lane = tid & 63, wave = tid >> 6;
  int c = lane & 15, kg = lane >> 4;
  // ---- issue score-phase K/Q/pos loads FIRST ----
  bf16x8 kv[4], qv[4];
  int pos_r[4];
  #pragma unroll
  for (int r=0;r<4;r++){
    int ed = rowbase + wave*16 + kg*4 + r;
    int sj = src[ed], dj = dst[ed];
    pos_r[r] = invpos[ed];
    kv[r] = *(const bf16x8*)(KbP + (size_t)sj*DD + c*8);
    qv[r] = *(const bf16x8*)(QbP + (size_t)dj*DD + c*8);
  }
  // ---- stage own wave's 16 rows: fp32 -> bf16 LDS (swizzled granules) ----
  {
    int row = wave*16 + (lane >> 2);
    int c0  = (lane & 3) * 32;
    const float* rp = e + (size_t)(rowbase+row)*DD + c0;
    #pragma unroll
    for (int g=0; g<4; ++g){
      float4 x = *(const float4*)(rp + g*8);
      float4 y = *(const float4*)(rp + g*8 + 4);
      bf16x8 v;
      v[0]=f2bf(x.x); v[1]=f2bf(x.y); v[2]=f2bf(x.z); v[3]=f2bf(x.w);
      v[4]=f2bf(y.x); v[5]=f2bf(y.y); v[6]=f2bf(y.z); v[7]=f2bf(y.w);
      int col8 = (c0 >> 3) + g;
      *(bf16x8*)&eL[row*DD + ((col8 ^ (row&7))<<3)] = v;
    }
  }
  // ---- MFMA: A from LDS (own wave's rows), B = WeT (L2-resident) ----
  f32x4 acc[8];
  #pragma unroll
  for (int j=0;j<8;j++) acc[j] = (f32x4){0.f,0.f,0.f,0.f};
  int arow = wave*16 + c;
  #pragma unroll
  for (int kc=0;kc<4;kc++){
    int col8 = kc*4 + kg;
    bf16x8 a = *(const bf16x8*)&eL[arow*DD + ((col8 ^ (arow&7))<<3)];
    int kb = kc*32 + kg*8;
    #pragma unroll
    for (int j=0;j<8;j++){
      bf16x8 b = *(const bf16x8*)(WeT + (j*16+c)*DD + kb);
      acc[j] = __builtin_amdgcn_mfma_f32_16x16x32_bf16(a, b, acc[j], 0,0,0);
    }
  }
  // ---- stats + in-place v = e + Eh (wave-private rows) ----
  float ssum[8], ssq[8];
  #pragma unroll
  for (int j=0;j<8;j++){ ssum[j]=0.f; ssq[j]=0.f; }
  #pragma unroll
  for (int r=0;r<4;r++){
    int le = wave*16 + kg*4 + r;
    int sw = le & 7;
    int rowoff = le*DD;
    #pragma unroll
    for (int j=0;j<8;j++){
      int col = j*16 + c;
      int sidx = rowoff + (((col>>3) ^ sw)<<3) + (col & 7);
      float v = bf2f(eL[sidx]) + acc[j][r];
      eL[sidx] = f2bf(v);
      ssum[j] += v; ssq[j] += v*v;
    }
  }
  #pragma unroll
  for (int j=0;j<8;j++){
    ssum[j] += __shfl_xor(ssum[j],16); ssum[j] += __shfl_xor(ssum[j],32);
    ssq[j]  += __shfl_xor(ssq[j],16);  ssq[j]  += __shfl_xor(ssq[j],32);
  }
  if (kg == 0){
    size_t pb = ((size_t)blockIdx.x*4 + wave)*256;
    #pragma unroll
    for (int j=0;j<8;j++){
      partB[pb + j*16 + c]       = f2bf(ssum[j]);
      partB[pb + 128 + j*16 + c] = f2bf(ssq[j]);
    }
  }
  // ---- scores: p_j = k*q*Eh, fold 8 regs over xor 8/4/2/1 (15 shfl) ----
  #pragma unroll
  for (int r=0;r<4;r++){
    float p0 = bf2f(kv[r][0])*bf2f(qv[r][0])*acc[0][r];
    float p1 = bf2f(kv[r][1])*bf2f(qv[r][1])*acc[1][r];
    float p2 = bf2f(kv[r][2])*bf2f(qv[r][2])*acc[2][r];
    float p3 = bf2f(kv[r][3])*bf2f(qv[r][3])*acc[3][r];
    float p4 = bf2f(kv[r][4])*bf2f(qv[r][4])*acc[4][r];
    float p5 = bf2f(kv[r][5])*bf2f(qv[r][5])*acc[5][r];
    float p6 = bf2f(kv[r][6])*bf2f(qv[r][6])*acc[6][r];
    float p7 = bf2f(kv[r][7])*bf2f(qv[r][7])*acc[7][r];
    float a0 = (c&8) ? (p4 + __shfl_xor(p4,8)) : (p0 + __shfl_xor(p0,8));
    float a1 = (c&8) ? (p5 + __shfl_xor(p5,8)) : (p1 + __shfl_xor(p1,8));
    float a2 = (c&8) ? (p6 + __shfl_xor(p6,8)) : (p2 + __shfl_xor(p2,8));
    float a3 = (c&8) ? (p7 + __shfl_xor(p7,8)) : (p3 + __shfl_xor(p3,8));
    float b0 = (c&4) ? (a2 + __shfl_xor(a2,4)) : (a0 + __shfl_xor(a0,4));
    float b1 = (c&4) ? (a3 + __shfl_xor(a3,4)) : (a1 + __shfl_xor(a1,4));
    float c0 = (c&2) ? (b1 + __shfl_xor(b1,2)) : (b0 + __shfl_xor(b0,2));
    float u  = c0 + __shfl_xor(c0,1);
    // lane c holds head (c>>1); even lanes write
    if (!(c & 1)){
      float s = __expf(fminf(fmaxf(u*0.25f,-5.f),5.f));
      sS[(size_t)pos_r[r]*8 + (c>>1)] = f2bf(s);
    }
  }
  // ---- copy-out e2pre bf16 (wave-local rows, 16B/lane coalesced) ----
  #pragma unroll
  for (int it=0; it<4; ++it){
    int row = wave*16 + it*4 + (lane>>4);
    int col8 = lane & 15;
    bf16x8 v = *(const bf16x8*)&eL[row*DD + ((col8 ^ (row&7))<<3)];
    *(bf16x8*)(e2p + (size_t)(rowbase+row)*DD + col8*8) = v;
  }
}

// ------- merged: node aggregation (blocks 0..12499) + e2 BN stream (rest) -------
// Gather now SEQUENTIAL in srcS/sS (CSR-sorted); only V-row gather is random.
__global__ __launch_bounds__(256) void agg_bn(
    const int* __restrict__ off, const int* __restrict__ srcS,
    const short* __restrict__ sS, const short* __restrict__ Vb,
    short* __restrict__ hA,
    const short* __restrict__ e2p, const float* __restrict__ ssE,
    float* __restrict__ e2){
  if (blockIdx.x >= 12500){
    size_t gi0 = (size_t)(blockIdx.x-12500)*256 + threadIdx.x;
    int col0 = (int)(gi0 & 15) * 8;
    float scr[8], shr[8];
    #pragma unroll
    for (int i=0;i<8;i++){ scr[i]=ssE[col0+i]; shr[i]=ssE[DD+col0+i]; }
    size_t stride = (size_t)2048*256;
    size_t total = (size_t)NEDGE*16;
    for (size_t gi = gi0; gi < total; gi += stride){
      bf16x8 v = *(const bf16x8*)(e2p + gi*8);
      float4 o0, o1;
      o0.x = bf2f(v[0])*scr[0]+shr[0];
      o0.y = bf2f(v[1])*scr[1]+shr[1];
      o0.z = bf2f(v[2])*scr[2]+shr[2];
      o0.w = bf2f(v[3])*scr[3]+shr[3];
      o1.x = bf2f(v[4])*scr[4]+shr[4];
      o1.y = bf2f(v[5])*scr[5]+shr[5];
      o1.z = bf2f(v[6])*scr[6]+shr[6];
      o1.w = bf2f(v[7])*scr[7]+shr[7];
      *(float4*)(e2 + gi*8)     = o0;
      *(float4*)(e2 + gi*8 + 4) = o1;
    }
    return;
  }
  int wave = threadIdx.x >> 6, lane = threadIdx.x & 63;
  int node = blockIdx.x*4 + wave;
  if (node >= NN) return;
  int beg = off[node], end = off[node+1];
  int col2 = lane*2;
  int hd = lane >> 3;
  float w0 = 0.f, w1 = 0.f, zh = 0.f;
  int ed = beg;
  for (; ed+3 < end; ed += 4){
    int sj0 = srcS[ed],   sj1 = srcS[ed+1];
    int sj2 = srcS[ed+2], sj3 = srcS[ed+3];
    float s0 = bf2f(sS[(size_t)(ed  )*8 + hd]);
    float s1 = bf2f(sS[(size_t)(ed+1)*8 + hd]);
    float s2 = bf2f(sS[(size_t)(ed+2)*8 + hd]);
    float s3 = bf2f(sS[(size_t)(ed+3)*8 + hd]);
    unsigned v0 = *(const unsigned*)(Vb + (size_t)sj0*DD + col2);
    unsigned v1 = *(const unsigned*)(Vb + (size_t)sj1*DD + col2);
    unsigned v2 = *(const unsigned*)(Vb + (size_t)sj2*DD + col2);
    unsigned v3 = *(const unsigned*)(Vb + (size_t)sj3*DD + col2);
    w0 += bf2f((short)(v0 & 0xffff))*s0 + bf2f((short)(v1 & 0xffff))*s1
        + bf2f((short)(v2 & 0xffff))*s2 + bf2f((short)(v3 & 0xffff))*s3;
    w1 += bf2f((short)(v0 >> 16))*s0 + bf2f((short)(v1 >> 16))*s1
        + bf2f((short)(v2 >> 16))*s2 + bf2f((short)(v3 >> 16))*s3;
    zh += s0 + s1 + s2 + s3;
  }
  for (; ed < end; ++ed){
    int sj = srcS[ed];
    float s = bf2f(sS[(size_t)ed*8 + hd]);
    unsigned vv = *(const unsigned*)(Vb + (size_t)sj*DD + col2);
    w0 += bf2f((short)(vv & 0xffff)) * s;
    w1 += bf2f((short)(vv >> 16)) * s;
    zh += s;
  }
  float inv = 1.f/(zh + 1e-6f);
  unsigned outv = (((unsigned)(unsigned short)f2bf(w1*inv)) << 16)
                |  ((unsigned)(unsigned short)f2bf(w0*inv));
  *(unsigned*)(hA + (size_t)node*DD + col2) = outv;
}

// ---- h2pre(bf16) = hA @ Wo + bo + h; per-wave fp32 partials, no barriers ----
__global__ __launch_bounds__(256) void attn_out(
    const short* __restrict__ hA,
    const short* __restrict__ WoT, const float* __restrict__ bo,
    const float* __restrict__ h, short* __restrict__ h2pre,
    float* __restrict__ part){
  int lane = threadIdx.x & 63, wave = threadIdx.x >> 6;
  int r16 = lane & 15, kg = lane >> 4;
  int rowbase = blockIdx.x*64 + wave*16;
  int arow = rowbase + r16; if (arow > NN-1) arow = NN-1;
  const short* Arow = hA + (size_t)arow*DD;
  f32x4 acc[8];
  #pragma unroll
  for (int j=0;j<8;j++) acc[j] = (f32x4){0.f,0.f,0.f,0.f};
  #pragma unroll
  for (int kc=0;kc<4;kc++){
    int kb = kc*32 + kg*8;
    bf16x8 a = *(const bf16x8*)(Arow + kb);
    #pragma unroll
    for (int j=0;j<8;j++){
      bf16x8 b = *(const bf16x8*)(WoT + (j*16+r16)*DD + kb);
      acc[j] = __builtin_amdgcn_mfma_f32_16x16x32_bf16(a, b, acc[j], 0,0,0);
    }
  }
  int orow0 = rowbase + kg*4;
  float ssum[8], ssq[8];
  #pragma unroll
  for (int j=0;j<8;j++){ ssum[j]=0.f; ssq[j]=0.f; }
  #pragma unroll
  for (int j=0;j<8;j++){
    #pragma unroll
    for (int r=0;r<4;r++){
      int row = orow0 + r;
      if (row < NN){
        int col = j*16 + r16;
        float v = acc[j][r] + bo[col] + h[(size_t)row*DD + col];
        h2pre[(size_t)row*DD + col] = f2bf(v);
        ssum[j] += v; ssq[j] += v*v;
      }
    }
  }
  #pragma unroll
  for (int j=0;j<8;j++){
    ssum[j] += __shfl_xor(ssum[j],16); ssum[j] += __shfl_xor(ssum[j],32);
    ssq[j]  += __shfl_xor(ssq[j],16);  ssq[j]  += __shfl_xor(ssq[j],32);
  }
  if (kg == 0){
    size_t pb = ((size_t)blockIdx.x*4 + wave)*256;
    #pragma unroll
    for (int j=0;j<8;j++){
      part[pb + j*16 + r16]       = ssum[j];
      part[pb + 128 + j*16 + r16] = ssq[j];
    }
  }
}

// ---------------- FFN1: relu(BN1(h2pre) @ W1 + b1) -> bf16 ----------------
__global__ __launch_bounds__(256) void ffn1_gemm(
    const short* __restrict__ h2pre, const float* __restrict__ ss1,
    const short* __restrict__ W1T, const float* __restrict__ b1,
    short* __restrict__ ffn1){
  int lane = threadIdx.x & 63, wave = threadIdx.x >> 6;
  int r16 = lane & 15, kg = lane >> 4;
  int rowbase = blockIdx.x*64 + wave*16;
  int arow = rowbase + r16; if (arow > NN-1) arow = NN-1;
  const short* Arow = h2pre + (size_t)arow*DD;
  f32x4 acc[16];
  #pragma unroll
  for (int j=0;j<16;j++) acc[j] = (f32x4){0.f,0.f,0.f,0.f};
  #pragma unroll
  for (int kc=0;kc<4;kc++){
    int kb = kc*32 + kg*8;
    bf16x8 raw = *(const bf16x8*)(Arow + kb);
    float4 s0 = *(const float4*)(ss1 + kb);
    float4 s1 = *(const float4*)(ss1 + kb + 4);
    float4 t0 = *(const float4*)(ss1 + DD + kb);
    float4 t1 = *(const float4*)(ss1 + DD + kb + 4);
    bf16x8 a;
    a[0]=f2bf(bf2f(raw[0])*s0.x+t0.x); a[1]=f2bf(bf2f(raw[1])*s0.y+t0.y);
    a[2]=f2bf(bf2f(raw[2])*s0.z+t0.z); a[3]=f2bf(bf2f(raw[3])*s0.w+t0.w);
    a[4]=f2bf(bf2f(raw[4])*s1.x+t1.x); a[5]=f2bf(bf2f(raw[5])*s1.y+t1.y);
    a[6]=f2bf(bf2f(raw[6])*s1.z+t1.z); a[7]=f2bf(bf2f(raw[7])*s1.w+t1.w);
    #pragma unroll
    for (int j=0;j<16;j++){
      bf16x8 b = *(const bf16x8*)(W1T + (j*16+r16)*DD + kb);
      acc[j] = __builtin_amdgcn_mfma_f32_16x16x32_bf16(a, b, acc[j], 0,0,0);
    }
  }
  int orow0 = rowbase + kg*4;
  #pragma unroll
  for (int j=0;j<16;j++){
    #pragma unroll
    for (int r=0;r<4;r++){
      int row = orow0 + r;
      if (row < NN){
        int col = j*16 + r16;
        float v = fmaxf(acc[j][r] + b1[col], 0.f);
        ffn1[(size_t)row*256 + col] = f2bf(v);
      }
    }
  }
}

// ---- FFN2: h3pre(bf16) = BN1(h2pre) + ffn1 @ W2 + b2; per-wave partials ----
__global__ __launch_bounds__(256) void ffn2_gemm(
    const short* __restrict__ ffn1, const short* __restrict__ W2T,
    const float* __restrict__ b2, const short* __restrict__ h2pre,
    const float* __restrict__ ss1, short* __restrict__ h3p,
    float* __restrict__ part){
  int lane = threadIdx.x & 63, wave = threadIdx.x >> 6;
  int r16 = lane & 15, kg = lane >> 4;
  int rowbase = blockIdx.x*64 + wave*16;
  int arow = rowbase + r16; if (arow > NN-1) arow = NN-1;
  const short* Arow = ffn1 + (size_t)arow*256;
  f32x4 acc[8];
  #pragma unroll
  for (int j=0;j<8;j++) acc[j] = (f32x4){0.f,0.f,0.f,0.f};
  #pragma unroll
  for (int kc=0;kc<8;kc++){
    int kb = kc*32 + kg*8;
    bf16x8 a = *(const bf16x8*)(Arow + kb);
    #pragma unroll
    for (int j=0;j<8;j++){
      bf16x8 b = *(const bf16x8*)(W2T + (j*16+r16)*256 + kb);
      acc[j] = __builtin_amdgcn_mfma_f32_16x16x32_bf16(a, b, acc[j], 0,0,0);
    }
  }
  int orow0 = rowbase + kg*4;
  float ssum[8], ssq[8];
  #pragma unroll
  for (int j=0;j<8;j++){ ssum[j]=0.f; ssq[j]=0.f; }
  #pragma unroll
  for (int j=0;j<8;j++){
    #pragma unroll
    for (int r=0;r<4;r++){
      int row = orow0 + r;
      if (row < NN){
        int col = j*16 + r16;
        float x = bf2f(h2pre[(size_t)row*DD + col]);
        float h2bn = x*ss1[col] + ss1[DD+col];
        float v = h2bn + acc[j][r] + b2[col];
        h3p[(size_t)row*DD + col] = f2bf(v);
        ssum[j] += v; ssq[j] += v*v;
      }
    }
  }
  #pragma unroll
  for (int j=0;j<8;j++){
    ssum[j] += __shfl_xor(ssum[j],16); ssum[j] += __shfl_xor(ssum[j],32);
    ssq[j]  += __shfl_xor(ssq[j],16);  ssq[j]  += __shfl_xor(ssq[j],32);
  }
  if (kg == 0){
    size_t pb = ((size_t)blockIdx.x*4 + wave)*256;
    #pragma unroll
    for (int j=0;j<8;j++){
      part[pb + j*16 + r16]       = ssum[j];
      part[pb + 128 + j*16 + r16] = ssq[j];
    }
  }
}

// ---------------- BN stats reduce (fp32 partials) ----------------
__global__ __launch_bounds__(256) void bn_reduce(
    const float* __restrict__ part, int nparts, float inv_n,
    const float* __restrict__ g, const float* __restrict__ b,
    float* __restrict__ ss){
  int col = blockIdx.x, t = threadIdx.x;
  float s = 0.f, q = 0.f;
  for (int i=t; i<nparts; i+=256){
    s += part[(size_t)i*256 + col];
    q += part[(size_t)i*256 + DD + col];
  }
  __shared__ float ls[256], lq[256];
  ls[t] = s; lq[t] = q; __syncthreads();
  for (int o2=128; o2>0; o2>>=1){
    if (t < o2){ ls[t] += ls[t+o2]; lq[t] += lq[t+o2]; }
    __syncthreads();
  }
  if (t == 0){
    float mean = ls[0]*inv_n;
    float var  = lq[0]*inv_n - mean*mean;
    float sc = g[col]*rsqrtf(var + 1e-5f);
    ss[col]      = sc;
    ss[DD + col] = b[col] - mean*sc;
  }
}

// ---------------- BN stats reduce (bf16 partials) ----------------
__global__ __launch_bounds__(256) void bn_reduce_bf16(
    const short* __restrict__ part, int nparts, float inv_n,
    const float* __restrict__ g, const float* __restrict__ b,
    float* __restrict__ ss){
  int col = blockIdx.x, t = threadIdx.x;
  float s = 0.f, q = 0.f;
  for (int i=t; i<nparts; i+=256){
    s += bf2f(part[(size_t)i*256 + col]);
    q += bf2f(part[(size_t)i*256 + DD + col]);
  }
  __shared__ float ls[256], lq[256];
  ls[t] = s; lq[t] = q; __syncthreads();
  for (int o2=128; o2>0; o2>>=1){
    if (t < o2){ ls[t] += ls[t+o2]; lq[t] += lq[t+o2]; }
    __syncthreads();
  }
  if (t == 0){
    float mean = ls[0]*inv_n;
    float var  = lq[0]*inv_n - mean*mean;
    float sc = g[col]*rsqrtf(var + 1e-5f);
    ss[col]      = sc;
    ss[DD + col] = b[col] - mean*sc;
  }
}

// ---- h3 = h3p(bf16)*scale + shift -> fp32 d_out (pure stream) ----
__global__ __launch_bounds__(256) void bn_apply_h(
    const short* __restrict__ h3p, const float* __restrict__ ss,
    float* __restrict__ h3){
  size_t gi = (size_t)blockIdx.x*256 + threadIdx.x;   // one granule of 8
  if (gi >= (size_t)NN*16) return;
  int col0 = (int)(gi & 15) * 8;
  bf16x8 v = *(const bf16x8*)(h3p + gi*8);
  float4 o0, o1;
  o0.x = bf2f(v[0])*ss[col0+0]+ss[DD+col0+0];
  o0.y = bf2f(v[1])*ss[col0+1]+ss[DD+col0+1];
  o0.z = bf2f(v[2])*ss[col0+2]+ss[DD+col0+2];
  o0.w = bf2f(v[3])*ss[col0+3]+ss[DD+col0+3];
  o1.x = bf2f(v[4])*ss[col0+4]+ss[DD+col0+4];
  o1.y = bf2f(v[5])*ss[col0+5]+ss[DD+col0+5];
  o1.z = bf2f(v[6])*ss[col0+6]+ss[DD+col0+6];
  o1.w = bf2f(v[7])*ss[col0+7]+ss[DD+col0+7];
  *(float4*)(h3 + gi*8)     = o0;
  *(float4*)(h3 + gi*8 + 4) = o1;
}

extern "C" void kernel_launch(void* const* d_in, const int* in_sizes, int n_in,
                              void* d_out, int out_size, void* d_ws, size_t ws_size,
                              hipStream_t stream){
  const float* h   = (const float*)d_in[0];
  const float* e   = (const float*)d_in[1];
  const int*   src = (const int*)d_in[2];
  const int*   dst = (const int*)d_in[3];
  const float* Wq  = (const float*)d_in[4];
  const float* Wk  = (const float*)d_in[5];
  const float* Wv  = (const float*)d_in[6];
  const float* We  = (const float*)d_in[7];
  const float* Wo  = (const float*)d_in[8];
  const float* bo  = (const float*)d_in[9];
  const float* g1h = (const float*)d_in[10];
  const float* b1h = (const float*)d_in[11];
  const float* g1e = (const float*)d_in[12];
  const float* b1e = (const float*)d_in[13];
  const float* W1  = (const float*)d_in[14];
  const float* b1  = (const float*)d_in[15];
  const float* W2  = (const float*)d_in[16];
  const float* b2  = (const float*)d_in[17];
  const float* g2h = (const float*)d_in[18];
  const float* b2h = (const float*)d_in[19];

  float* out = (float*)d_out;
  float* h3  = out;                       // [NN][128]
  float* e2  = out + (size_t)NN*DD;       // [NEDGE][128]

  char* ws = (char*)d_ws;
  size_t off_b = 0;
  auto take = [&](size_t bytes)->char*{
    char* p = ws + off_b; off_b = (off_b + bytes + 255) & ~(size_t)255; return p;
  };
  short* wT     = (short*)take((size_t)147456*2);
  float* ssE    = (float*)take(256*4);
  float* ss1    = (float*)take(256*4);
  float* ss2    = (float*)take(256*4);
  short* QbP    = (short*)take((size_t)NN*DD*2);
  short* KbP    = (short*)take((size_t)NN*DD*2);
  short* Vb     = (short*)take((size_t)NN*DD*2);
  short* hA     = (short*)take((size_t)NN*DD*2);
  short* e2p    = (short*)take((size_t)NEDGE*DD*2);
  short* sS     = (short*)take((size_t)NEDGE*8*2);
  int*   cnt2   = (int*)take((size_t)2*NN*4);     // counts | cursor
  int*   counts = cnt2;
  int*   cursor = cnt2 + NN;
  int*   offs   = (int*)take((size_t)(NN+1)*4);
  int*   invpos = (int*)take((size_t)NEDGE*4);
  int*   srcS   = (int*)take((size_t)NEDGE*4);
  int*   bsum   = (int*)take((size_t)256*4);
  int*   bbase  = (int*)take((size_t)256*4);
  short* h2pre  = (short*)take((size_t)NN*DD*2);
  short* ffn1   = (short*)take((size_t)NN*256*2);
  short* h3p    = (short*)take((size_t)NN*DD*2);
  short* partEB = (short*)take((size_t)32000*256*2);
  float* partH2 = (float*)take((size_t)3128*256*4);
  float* partH3 = (float*)take((size_t)3128*256*4);

  hipMemsetAsync(cnt2, 0, (size_t)2*NN*4, stream);

  prep_hist<<<2576,256,0,stream>>>(Wq,Wk,Wv,We,Wo,W1,W2,wT, dst, counts);
  scan_p1<<<SCAN_NB,256,0,stream>>>(counts, bsum);
  scan_p2<<<1,256,0,stream>>>(bsum, bbase);
  scan_p3<<<SCAN_NB,256,0,stream>>>(counts, bbase, offs);
  qkv_scatter<<<2782,256,0,stream>>>(h, wT, QbP, KbP, Vb, src, dst, offs,
                                     cursor, invpos, srcS);
  edge_fused<<<8000,256,0,stream>>>(e, wT+49152, QbP, KbP, src, dst, invpos,
                                    e2p, sS, partEB);
  bn_reduce_bf16<<<128,256,0,stream>>>(partEB, 32000, 1.f/(float)NEDGE, g1e, b1e, ssE);
  agg_bn<<<14548,256,0,stream>>>(offs, srcS, sS, Vb, hA, e2p, ssE, e2);
  attn_out<<<782,256,0,stream>>>(hA, wT+65536, bo, h, h2pre, partH2);
  bn_reduce<<<128,256,0,stream>>>(partH2, 3128, 1.f/(float)NN, g1h, b1h, ss1);
  ffn1_gemm<<<782,256,0,stream>>>(h2pre, ss1, wT+81920, b1, ffn1);
  ffn2_gemm<<<782,256,0,stream>>>(ffn1, wT+114688, b2, h2pre, ss1, h3p, partH3);
  bn_reduce<<<128,256,0,stream>>>(partH3, 3128, 1.f/(float)NN, g2h, b2h, ss2);
  bn_apply_h<<<3125,256,0,stream>>>(h3p, ss2, h3);
}